// Round 11
// baseline (862.299 us; speedup 1.0000x reference)
//
#include <hip/hip_runtime.h>
#include <hip/hip_bf16.h>

#define NTOT  1048576
#define MWG   128          // rows per workgroup
#define BLK   128          // threads (2 waves x 64 rows each)
#define ROWB  384          // act row stride in bytes (192 bf16)
#define ACT_BYTES  (MWG * ROWB)          // 49152

typedef __attribute__((ext_vector_type(8))) short  bf16x8;
typedef __attribute__((ext_vector_type(4))) float  f32x4;

__device__ __forceinline__ unsigned short f2bf(float f) {
  unsigned u = __float_as_uint(f);
  u += 0x7fffu + ((u >> 16) & 1u);          // RNE
  return (unsigned short)(u >> 16);
}

__device__ __forceinline__ unsigned pk2bf(float lo, float hi) {
  float2 t; t.x = lo; t.y = hi;
  __hip_bfloat162 b = __float22bfloat162_rn(t);   // RNE
  return *(unsigned*)&b;
}

// ---------------- weight prepack ----------------
// fp32 [k][n] (concat-reorder / zero-pad) -> bf16 MFMA-fragment order:
// dst idx = (((nt*KS + ks)*4 + lg)*16 + l15)*8 + e   for n = nt*16+l15, k = ks*32+lg*8+e
__global__ __launch_bounds__(256) void prepack_k(
    const float* __restrict__ s0, const float* __restrict__ s1,
    const float* __restrict__ s2, const float* __restrict__ s3,
    const float* __restrict__ s4, const float* __restrict__ s5,
    const float* __restrict__ s6, const float* __restrict__ s7,
    const float* __restrict__ s8, const float* __restrict__ s9,
    const float* __restrict__ s10, unsigned short* __restrict__ dst)
{
  const int nw_[11]  = {128,128,128,128,128,128,128,128,144, 64, 16};
  const int kw_[11]  = { 64,128,128,128,128,192,128,128,128,192, 64};
  const int nc_[11]  = {128,128,128,128,128,128,128,128,129, 64,  3};
  const int k1_[11]  = { 63,128,128,128,128, 63,128,128,128, 27, 64};
  const int o1_[11]  = {  0,  0,  0,  0,  0,128,  0,  0,  0,128,  0};
  const int k2_[11]  = {999,999,999,999,999, 64,999,999,999, 64,999};
  const int do_[11]  = {0,8192,24576,40960,57344,73728,98304,114688,131072,149504,161792};

  int c = blockIdx.x;
  const float* src =
    c==0?s0: c==1?s1: c==2?s2: c==3?s3: c==4?s4: c==5?s5:
    c==6?s6: c==7?s7: c==8?s8: c==9?s9: s10;
  int nw=nw_[c], kw=kw_[c], nc=nc_[c], k1=k1_[c], o1=o1_[c], k2=k2_[c];
  int KS = kw >> 5;
  int total = nw * kw;
  for (int idx = blockIdx.y * blockDim.x + threadIdx.x; idx < total;
       idx += gridDim.y * blockDim.x) {
    int e   = idx & 7;
    int l15 = (idx >> 3) & 15;
    int lg  = (idx >> 7) & 3;
    int r   = idx >> 9;
    int ks  = r % KS;
    int nt  = r / KS;
    int n = nt * 16 + l15;
    int k = ks * 32 + lg * 8 + e;
    float v = 0.f;
    if (n < nc) {
      if (k < k1)       v = src[(o1 + k) * nc + n];
      else if (k >= k2) v = src[(k - k2) * nc + n];
    }
    dst[do_[c] + idx] = f2bf(v);
  }
}

// ---------------- posenc: 32 cols of one row, all indices compile-time ----------------
template<int I0, int L>
__device__ __forceinline__ void posenc_store(unsigned char* actb, int row,
                                             float p0, float p1, float p2)
{
#pragma unroll
  for (int q = 0; q < 4; q++) {
    float hv[8];
#pragma unroll
    for (int e = 0; e < 8; e++) {
      const int i = I0 + q * 8 + e;
      float v;
      if (i == 0) v = p0;
      else if (i == 1) v = p1;
      else if (i == 2) v = p2;
      else {
        const int idx = i - 3, j = idx / 6, t = idx % 6;
        if (j < L) {
          const float sc = (float)(1 << j);
          const float a  = (t % 3 == 0 ? p0 : (t % 3 == 1 ? p1 : p2)) * sc;
          v = (t < 3) ? __sinf(a) : __cosf(a);
        } else v = 0.f;
      }
      hv[e] = v;
    }
    uint4 pk;
    pk.x = pk2bf(hv[0], hv[1]);
    pk.y = pk2bf(hv[2], hv[3]);
    pk.z = pk2bf(hv[4], hv[5]);
    pk.w = pk2bf(hv[6], hv[7]);
    int b = (row * ROWB + (I0 + q * 8) * 2) ^ ((row & 7) << 4);
    *(uint4*)(actb + b) = pk;
  }
}

// ---------------- one layer, fully inlined, 64 rows/wave ----------------
// weights from global in fragment order (L2-resident), act in LDS.
// D[n][m] = sum_k Wt[n][k] * act[m][KB+k]
// afr loaded ONE at a time (keeps arch-VGPR pressure ~90 so acc[4][NT] AGPRs +
// arch fit the 256/wave budget at 2 waves/SIMD); ks=0 peeled with vzero as C.
// All LDS reads precede epilogue writes -> in-place update race-free per wave.
// MODE 0: relu -> act.  MODE 1: feat no-relu -> act; nt==8 sigma -> out.  MODE 2: sigmoid color -> out.
template<int KS, int NT, int MODE, int KB, int DST>
__device__ __forceinline__ void layer_g(
    unsigned char* actb, const unsigned short* __restrict__ wchunk,
    int mbase, int lane, float* __restrict__ out, long grow0)
{
  const int l15 = lane & 15;
  const int lg  = lane >> 4;
  const unsigned short* wl = wchunk + lane * 8;
  const f32x4 vzero = {0.f, 0.f, 0.f, 0.f};
  f32x4 acc[4][NT];

#pragma unroll
  for (int ks = 0; ks < KS; ks++) {
    const int kloc = ks * 32 + lg * 8;
    bf16x8 bfr[4];
#pragma unroll
    for (int mt = 0; mt < 4; mt++) {
      int m = mbase + mt * 16 + l15;
      int byt = (m * ROWB + (KB + kloc) * 2) ^ ((m & 7) << 4);
      bfr[mt] = *(const bf16x8*)(actb + byt);
    }
#pragma unroll
    for (int nt = 0; nt < NT; nt++) {
      bf16x8 afr = *(const bf16x8*)(wl + (nt * KS + ks) * 512);
#pragma unroll
      for (int mt = 0; mt < 4; mt++) {
        if (ks == 0)
          acc[mt][nt] = __builtin_amdgcn_mfma_f32_16x16x32_bf16(afr, bfr[mt], vzero, 0, 0, 0);
        else
          acc[mt][nt] = __builtin_amdgcn_mfma_f32_16x16x32_bf16(afr, bfr[mt], acc[mt][nt], 0, 0, 0);
      }
    }
  }

#pragma unroll
  for (int mt = 0; mt < 4; mt++) {
    int m = mbase + mt * 16 + l15;
#pragma unroll
    for (int nt = 0; nt < NT; nt++) {
      f32x4 v = acc[mt][nt];
      if (MODE == 1 && nt == 8) {               // sigma (n==128 -> lg==0, reg 0)
        if (lg == 0) out[3L * NTOT + grow0 + m] = fmaxf(v.x, 0.f);
      } else if (MODE == 2) {                   // color, n=0..2 -> lg==0 regs x,y,z
        if (lg == 0) {
          long g3 = (grow0 + m) * 3;
          out[g3 + 0] = 1.f / (1.f + __expf(-v.x));
          out[g3 + 1] = 1.f / (1.f + __expf(-v.y));
          out[g3 + 2] = 1.f / (1.f + __expf(-v.z));
        }
      } else {
        if (MODE == 0) {
          v.x = fmaxf(v.x, 0.f); v.y = fmaxf(v.y, 0.f);
          v.z = fmaxf(v.z, 0.f); v.w = fmaxf(v.w, 0.f);
        }
        uint2 pk;
        pk.x = pk2bf(v.x, v.y);
        pk.y = pk2bf(v.z, v.w);
        int col = DST + nt * 16 + lg * 4;       // 4 consecutive features, fixed row
        int byt = (m * ROWB + col * 2) ^ ((m & 7) << 4);
        *(uint2*)(actb + byt) = pk;
      }
    }
  }
}

__global__ __launch_bounds__(BLK, 2) void nerf_fused(
    const float* __restrict__ pos, const float* __restrict__ dirs,
    const unsigned short* __restrict__ wp, float* __restrict__ out)
{
  __shared__ unsigned char actb[ACT_BYTES];   // act[128][192] bf16, swizzled rows

  const int tid   = threadIdx.x;
  const int lane  = tid & 63;
  const int mbase = (tid >> 6) * 64;          // wave owns 64 rows end-to-end
  const long grow0 = (long)blockIdx.x * MWG;

  const int row = tid;                         // 1 thread = 1 row
  const long g  = grow0 + row;

  // posenc(pos) -> cols 0..62 (col 63 = 0); wave-local rows, no barrier anywhere
  {
    float p0 = pos[g * 3 + 0], p1 = pos[g * 3 + 1], p2 = pos[g * 3 + 2];
    posenc_store<0, 10>(actb, row, p0, p1, p2);
    posenc_store<32, 10>(actb, row, p0, p1, p2);
  }

  layer_g<2, 8, 0,  0, 64>(actb, wp +      0, mbase, lane, out, grow0);  // b1_w0
  layer_g<4, 8, 0, 64, 64>(actb, wp +   8192, mbase, lane, out, grow0);  // b1_w1
  layer_g<4, 8, 0, 64, 64>(actb, wp +  24576, mbase, lane, out, grow0);  // b1_w2
  layer_g<4, 8, 0, 64, 64>(actb, wp +  40960, mbase, lane, out, grow0);  // b1_w3
  layer_g<4, 8, 0, 64, 64>(actb, wp +  57344, mbase, lane, out, grow0);  // b1_w4
  layer_g<6, 8, 0,  0, 64>(actb, wp +  73728, mbase, lane, out, grow0);  // b2_w0 (K=192)

  // posenc(dirs) -> cols 0..26, 27..63 = 0 (x_emb dead; own rows only)
  {
    float p0 = dirs[g * 3 + 0], p1 = dirs[g * 3 + 1], p2 = dirs[g * 3 + 2];
    posenc_store<0, 4>(actb, row, p0, p1, p2);
    posenc_store<32, 4>(actb, row, p0, p1, p2);   // all zeros
  }

  layer_g<4, 8, 0, 64, 64>(actb, wp +  98304, mbase, lane, out, grow0);  // b2_w1
  layer_g<4, 8, 0, 64, 64>(actb, wp + 114688, mbase, lane, out, grow0);  // b2_w2
  layer_g<4, 9, 1, 64, 64>(actb, wp + 131072, mbase, lane, out, grow0);  // b2_w3 + sigma
  layer_g<6, 4, 0,  0,  0>(actb, wp + 149504, mbase, lane, out, grow0);  // b3_w0 (K=192) -> cols 0..63
  layer_g<2, 1, 2,  0,  0>(actb, wp + 161792, mbase, lane, out, grow0);  // b3_w1 -> color
}

extern "C" void kernel_launch(void* const* d_in, const int* in_sizes, int n_in,
                              void* d_out, int out_size, void* d_ws, size_t ws_size,
                              hipStream_t stream)
{
  const float* pos  = (const float*)d_in[0];
  const float* dirs = (const float*)d_in[1];
  unsigned short* wpack = (unsigned short*)d_ws;   // 325,632 B used
  float* out = (float*)d_out;

  prepack_k<<<dim3(11, 12, 1), 256, 0, stream>>>(
      (const float*)d_in[2], (const float*)d_in[3], (const float*)d_in[4],
      (const float*)d_in[5], (const float*)d_in[6], (const float*)d_in[7],
      (const float*)d_in[8], (const float*)d_in[9], (const float*)d_in[10],
      (const float*)d_in[11], (const float*)d_in[12], wpack);

  nerf_fused<<<NTOT / MWG, BLK, 0, stream>>>(pos, dirs, wpack, out);
}

// Round 12
// 543.245 us; speedup vs baseline: 1.5873x; 1.5873x over previous
//
#include <hip/hip_runtime.h>
#include <hip/hip_bf16.h>

#define NTOT  1048576
#define MWG   128          // rows per workgroup
#define BLK   256          // threads (4 waves); N-split: wave w owns output tiles {2w,2w+1}
#define ROWB  384          // act row stride in bytes (192 bf16)
#define ACT_BYTES  (MWG * ROWB)          // 49152

typedef __attribute__((ext_vector_type(8))) short  bf16x8;
typedef __attribute__((ext_vector_type(4))) float  f32x4;

__device__ __forceinline__ unsigned short f2bf(float f) {
  unsigned u = __float_as_uint(f);
  u += 0x7fffu + ((u >> 16) & 1u);          // RNE
  return (unsigned short)(u >> 16);
}

__device__ __forceinline__ unsigned pk2bf(float lo, float hi) {
  float2 t; t.x = lo; t.y = hi;
  __hip_bfloat162 b = __float22bfloat162_rn(t);   // RNE
  return *(unsigned*)&b;
}

// ---------------- weight prepack (identical to R6) ----------------
// fp32 [k][n] (concat-reorder / zero-pad) -> bf16 MFMA-fragment order:
// dst idx = (((nt*KS + ks)*4 + lg)*16 + l15)*8 + e   for n = nt*16+l15, k = ks*32+lg*8+e
__global__ __launch_bounds__(256) void prepack_k(
    const float* __restrict__ s0, const float* __restrict__ s1,
    const float* __restrict__ s2, const float* __restrict__ s3,
    const float* __restrict__ s4, const float* __restrict__ s5,
    const float* __restrict__ s6, const float* __restrict__ s7,
    const float* __restrict__ s8, const float* __restrict__ s9,
    const float* __restrict__ s10, unsigned short* __restrict__ dst)
{
  const int nw_[11]  = {128,128,128,128,128,128,128,128,144, 64, 16};
  const int kw_[11]  = { 64,128,128,128,128,192,128,128,128,192, 64};
  const int nc_[11]  = {128,128,128,128,128,128,128,128,129, 64,  3};
  const int k1_[11]  = { 63,128,128,128,128, 63,128,128,128, 27, 64};
  const int o1_[11]  = {  0,  0,  0,  0,  0,128,  0,  0,  0,128,  0};
  const int k2_[11]  = {999,999,999,999,999, 64,999,999,999, 64,999};
  const int do_[11]  = {0,8192,24576,40960,57344,73728,98304,114688,131072,149504,161792};

  int c = blockIdx.x;
  const float* src =
    c==0?s0: c==1?s1: c==2?s2: c==3?s3: c==4?s4: c==5?s5:
    c==6?s6: c==7?s7: c==8?s8: c==9?s9: s10;
  int nw=nw_[c], kw=kw_[c], nc=nc_[c], k1=k1_[c], o1=o1_[c], k2=k2_[c];
  int KS = kw >> 5;
  int total = nw * kw;
  for (int idx = blockIdx.y * blockDim.x + threadIdx.x; idx < total;
       idx += gridDim.y * blockDim.x) {
    int e   = idx & 7;
    int l15 = (idx >> 3) & 15;
    int lg  = (idx >> 7) & 3;
    int r   = idx >> 9;
    int ks  = r % KS;
    int nt  = r / KS;
    int n = nt * 16 + l15;
    int k = ks * 32 + lg * 8 + e;
    float v = 0.f;
    if (n < nc) {
      if (k < k1)       v = src[(o1 + k) * nc + n];
      else if (k >= k2) v = src[(k - k2) * nc + n];
    }
    dst[do_[c] + idx] = f2bf(v);
  }
}

// ---------------- posenc: 32 cols of one row, all indices compile-time ----------------
template<int I0, int L>
__device__ __forceinline__ void posenc_store(unsigned char* actb, int row,
                                             float p0, float p1, float p2)
{
#pragma unroll
  for (int q = 0; q < 4; q++) {
    float hv[8];
#pragma unroll
    for (int e = 0; e < 8; e++) {
      const int i = I0 + q * 8 + e;
      float v;
      if (i == 0) v = p0;
      else if (i == 1) v = p1;
      else if (i == 2) v = p2;
      else {
        const int idx = i - 3, j = idx / 6, t = idx % 6;
        if (j < L) {
          const float sc = (float)(1 << j);
          const float a  = (t % 3 == 0 ? p0 : (t % 3 == 1 ? p1 : p2)) * sc;
          v = (t < 3) ? __sinf(a) : __cosf(a);
        } else v = 0.f;
      }
      hv[e] = v;
    }
    uint4 pk;
    pk.x = pk2bf(hv[0], hv[1]);
    pk.y = pk2bf(hv[2], hv[3]);
    pk.z = pk2bf(hv[4], hv[5]);
    pk.w = pk2bf(hv[6], hv[7]);
    int b = (row * ROWB + (I0 + q * 8) * 2) ^ ((row & 7) << 4);
    *(uint4*)(actb + b) = pk;
  }
}

// ---------------- N-split layer: wave computes NTP output tiles for ALL 128 rows ----------------
// D[n][m] = sum_k Wt[n][k] * act[m][KB+k], n in [ntbase*16, (ntbase+NTP)*16)
// Weight reads per wave = NTP*KS fragments (4x fewer than per-wave-full-N).
// MIDBAR: barrier between all-reads and writes (in-place layers). End barrier always.
// SIG: additionally compute sigma tile (chunk nt==8) for m-tiles {2*wid, 2*wid+1} -> out.
// RELU: apply relu before store.
template<int KS, int NTP, int KB, int DST, bool RELU, bool MIDBAR, bool SIG>
__device__ __forceinline__ void layer_n(
    unsigned char* actb, const unsigned short* __restrict__ wchunk,
    int ntbase, int lane, int wid, float* __restrict__ out, long grow0)
{
  const int l15 = lane & 15;
  const int lg  = lane >> 4;
  const unsigned short* wl = wchunk + ntbase * (KS * 512) + lane * 8;
  const f32x4 vzero = {0.f, 0.f, 0.f, 0.f};
  f32x4 acc[8][NTP];
  f32x4 accs[2];

#pragma unroll
  for (int ks = 0; ks < KS; ks++) {
    const int kloc = ks * 32 + lg * 8;
    bf16x8 bfr[8];
#pragma unroll
    for (int mt = 0; mt < 8; mt++) {
      int m = mt * 16 + l15;
      int byt = (m * ROWB + (KB + kloc) * 2) ^ ((m & 7) << 4);
      bfr[mt] = *(const bf16x8*)(actb + byt);
    }
#pragma unroll
    for (int nt = 0; nt < NTP; nt++) {
      bf16x8 afr = *(const bf16x8*)(wl + (nt * KS + ks) * 512);
#pragma unroll
      for (int mt = 0; mt < 8; mt++) {
        if (ks == 0)
          acc[mt][nt] = __builtin_amdgcn_mfma_f32_16x16x32_bf16(afr, bfr[mt], vzero, 0, 0, 0);
        else
          acc[mt][nt] = __builtin_amdgcn_mfma_f32_16x16x32_bf16(afr, bfr[mt], acc[mt][nt], 0, 0, 0);
      }
    }
    if (SIG) {   // sigma tile (chunk nt==8), m-tiles {2*wid, 2*wid+1}
      bf16x8 afs = *(const bf16x8*)(wchunk + (8 * KS + ks) * 512 + lane * 8);
#pragma unroll
      for (int j = 0; j < 2; j++) {
        int m = (2 * wid + j) * 16 + l15;
        int byt = (m * ROWB + (KB + kloc) * 2) ^ ((m & 7) << 4);
        bf16x8 bfs = *(const bf16x8*)(actb + byt);
        if (ks == 0)
          accs[j] = __builtin_amdgcn_mfma_f32_16x16x32_bf16(afs, bfs, vzero, 0, 0, 0);
        else
          accs[j] = __builtin_amdgcn_mfma_f32_16x16x32_bf16(afs, bfs, accs[j], 0, 0, 0);
      }
    }
  }

  if (MIDBAR) __syncthreads();     // all reads of old act done before any write

#pragma unroll
  for (int mt = 0; mt < 8; mt++) {
    int m = mt * 16 + l15;
#pragma unroll
    for (int nt = 0; nt < NTP; nt++) {
      f32x4 v = acc[mt][nt];
      if (RELU) {
        v.x = fmaxf(v.x, 0.f); v.y = fmaxf(v.y, 0.f);
        v.z = fmaxf(v.z, 0.f); v.w = fmaxf(v.w, 0.f);
      }
      uint2 pk;
      pk.x = pk2bf(v.x, v.y);
      pk.y = pk2bf(v.z, v.w);
      int col = DST + (ntbase + nt) * 16 + lg * 4;
      int byt = (m * ROWB + col * 2) ^ ((m & 7) << 4);
      *(uint2*)(actb + byt) = pk;
    }
  }
  if (SIG && lg == 0) {
#pragma unroll
    for (int j = 0; j < 2; j++) {
      int m = (2 * wid + j) * 16 + l15;
      out[3L * NTOT + grow0 + m] = fmaxf(accs[j].x, 0.f);
    }
  }
  __syncthreads();                 // writes visible before next layer reads
}

// color: single n-tile, m-split {2*wid, 2*wid+1}; reads c1 cols 0..63; writes global only
__device__ __forceinline__ void color_n(
    unsigned char* actb, const unsigned short* __restrict__ wchunk,
    int lane, int wid, float* __restrict__ out, long grow0)
{
  const int l15 = lane & 15;
  const int lg  = lane >> 4;
  const f32x4 vzero = {0.f, 0.f, 0.f, 0.f};
  f32x4 acc[2];
#pragma unroll
  for (int ks = 0; ks < 2; ks++) {
    const int kloc = ks * 32 + lg * 8;
    bf16x8 afr = *(const bf16x8*)(wchunk + ks * 512 + lane * 8);
#pragma unroll
    for (int j = 0; j < 2; j++) {
      int m = (2 * wid + j) * 16 + l15;
      int byt = (m * ROWB + kloc * 2) ^ ((m & 7) << 4);
      bf16x8 bfr = *(const bf16x8*)(actb + byt);
      if (ks == 0) acc[j] = __builtin_amdgcn_mfma_f32_16x16x32_bf16(afr, bfr, vzero, 0, 0, 0);
      else         acc[j] = __builtin_amdgcn_mfma_f32_16x16x32_bf16(afr, bfr, acc[j], 0, 0, 0);
    }
  }
  if (lg == 0) {
#pragma unroll
    for (int j = 0; j < 2; j++) {
      int m = (2 * wid + j) * 16 + l15;
      long g3 = (grow0 + m) * 3;
      out[g3 + 0] = 1.f / (1.f + __expf(-acc[j].x));
      out[g3 + 1] = 1.f / (1.f + __expf(-acc[j].y));
      out[g3 + 2] = 1.f / (1.f + __expf(-acc[j].z));
    }
  }
}

__global__ __launch_bounds__(BLK, 3) void nerf_fused(
    const float* __restrict__ pos, const float* __restrict__ dirs,
    const unsigned short* __restrict__ wp, float* __restrict__ out)
{
  __shared__ unsigned char actb[ACT_BYTES];   // act[128][192] bf16, swizzled rows

  const int tid   = threadIdx.x;
  const int lane  = tid & 63;
  const int wid   = tid >> 6;
  const long grow0 = (long)blockIdx.x * MWG;

  const int row = wid * 32 + (lane & 31);
  const long g  = grow0 + row;

  // posenc(pos) -> cols 0..62 (col 63 = 0), own rows
  {
    float p0 = pos[g * 3 + 0], p1 = pos[g * 3 + 1], p2 = pos[g * 3 + 2];
    if (lane < 32) posenc_store<0, 10>(actb, row, p0, p1, p2);
    else           posenc_store<32, 10>(actb, row, p0, p1, p2);
  }
  __syncthreads();

  // b1_w0: reads cols 0..63, writes 64..191 (disjoint -> no midbar)
  layer_n<2, 2, 0, 64, true, false, false>(actb, wp +      0, wid*2, lane, wid, out, grow0);
  layer_n<4, 2, 64, 64, true, true, false>(actb, wp +   8192, wid*2, lane, wid, out, grow0); // b1_w1
  layer_n<4, 2, 64, 64, true, true, false>(actb, wp +  24576, wid*2, lane, wid, out, grow0); // b1_w2
  layer_n<4, 2, 64, 64, true, true, false>(actb, wp +  40960, wid*2, lane, wid, out, grow0); // b1_w3
  layer_n<4, 2, 64, 64, true, true, false>(actb, wp +  57344, wid*2, lane, wid, out, grow0); // b1_w4
  // b2_w0: K=192 reads 0..191, writes 64..191
  layer_n<6, 2, 0, 64, true, true, false>(actb, wp +  73728, wid*2, lane, wid, out, grow0);

  // posenc(dirs) -> cols 0..26 (27..63 zero), own rows; consumed only by b3_w0
  // (safe: b2_w0's reads of cols 0..63 are fenced by its midbar; next layers read 64..191)
  {
    float p0 = dirs[g * 3 + 0], p1 = dirs[g * 3 + 1], p2 = dirs[g * 3 + 2];
    if (lane < 32) posenc_store<0, 4>(actb, row, p0, p1, p2);
    else           posenc_store<32, 4>(actb, row, p0, p1, p2);   // all zeros
  }

  layer_n<4, 2, 64, 64, true, true, false>(actb, wp +  98304, wid*2, lane, wid, out, grow0); // b2_w1
  layer_n<4, 2, 64, 64, true, true, false>(actb, wp + 114688, wid*2, lane, wid, out, grow0); // b2_w2
  // b2_w3: feat (no relu) + sigma tile (SIG)
  layer_n<4, 2, 64, 64, false, true, true>(actb, wp + 131072, wid*2, lane, wid, out, grow0);
  // b3_w0: K=192 reads 0..191 (d_emb|feat), writes c1 cols 0..63
  layer_n<6, 1, 0, 0, true, true, false>(actb, wp + 149504, wid, lane, wid, out, grow0);
  // b3_w1 -> color (global only)
  color_n(actb, wp + 161792, lane, wid, out, grow0);
}

extern "C" void kernel_launch(void* const* d_in, const int* in_sizes, int n_in,
                              void* d_out, int out_size, void* d_ws, size_t ws_size,
                              hipStream_t stream)
{
  const float* pos  = (const float*)d_in[0];
  const float* dirs = (const float*)d_in[1];
  unsigned short* wpack = (unsigned short*)d_ws;   // 325,632 B used
  float* out = (float*)d_out;

  prepack_k<<<dim3(11, 12, 1), 256, 0, stream>>>(
      (const float*)d_in[2], (const float*)d_in[3], (const float*)d_in[4],
      (const float*)d_in[5], (const float*)d_in[6], (const float*)d_in[7],
      (const float*)d_in[8], (const float*)d_in[9], (const float*)d_in[10],
      (const float*)d_in[11], (const float*)d_in[12], wpack);

  nerf_fused<<<NTOT / MWG, BLK, 0, stream>>>(pos, dirs, wpack, out);
}

// Round 13
// 535.149 us; speedup vs baseline: 1.6113x; 1.0151x over previous
//
#include <hip/hip_runtime.h>
#include <hip/hip_bf16.h>

#define NTOT  1048576
#define MWG   128          // rows per workgroup
#define BLK   256          // threads (4 waves); N-split: wave w owns output tiles {2w,2w+1}
#define ROWB  384          // act row stride in bytes (192 bf16)
#define ACT_BYTES  (MWG * ROWB)          // 49152

typedef __attribute__((ext_vector_type(8))) short  bf16x8;
typedef __attribute__((ext_vector_type(4))) float  f32x4;

__device__ __forceinline__ unsigned short f2bf(float f) {
  unsigned u = __float_as_uint(f);
  u += 0x7fffu + ((u >> 16) & 1u);          // RNE
  return (unsigned short)(u >> 16);
}

__device__ __forceinline__ unsigned pk2bf(float lo, float hi) {
  float2 t; t.x = lo; t.y = hi;
  __hip_bfloat162 b = __float22bfloat162_rn(t);   // RNE
  return *(unsigned*)&b;
}

// ---------------- weight prepack (identical to R6/R12) ----------------
// fp32 [k][n] (concat-reorder / zero-pad) -> bf16 MFMA-fragment order:
// dst idx = (((nt*KS + ks)*4 + lg)*16 + l15)*8 + e   for n = nt*16+l15, k = ks*32+lg*8+e
__global__ __launch_bounds__(256) void prepack_k(
    const float* __restrict__ s0, const float* __restrict__ s1,
    const float* __restrict__ s2, const float* __restrict__ s3,
    const float* __restrict__ s4, const float* __restrict__ s5,
    const float* __restrict__ s6, const float* __restrict__ s7,
    const float* __restrict__ s8, const float* __restrict__ s9,
    const float* __restrict__ s10, unsigned short* __restrict__ dst)
{
  const int nw_[11]  = {128,128,128,128,128,128,128,128,144, 64, 16};
  const int kw_[11]  = { 64,128,128,128,128,192,128,128,128,192, 64};
  const int nc_[11]  = {128,128,128,128,128,128,128,128,129, 64,  3};
  const int k1_[11]  = { 63,128,128,128,128, 63,128,128,128, 27, 64};
  const int o1_[11]  = {  0,  0,  0,  0,  0,128,  0,  0,  0,128,  0};
  const int k2_[11]  = {999,999,999,999,999, 64,999,999,999, 64,999};
  const int do_[11]  = {0,8192,24576,40960,57344,73728,98304,114688,131072,149504,161792};

  int c = blockIdx.x;
  const float* src =
    c==0?s0: c==1?s1: c==2?s2: c==3?s3: c==4?s4: c==5?s5:
    c==6?s6: c==7?s7: c==8?s8: c==9?s9: s10;
  int nw=nw_[c], kw=kw_[c], nc=nc_[c], k1=k1_[c], o1=o1_[c], k2=k2_[c];
  int KS = kw >> 5;
  int total = nw * kw;
  for (int idx = blockIdx.y * blockDim.x + threadIdx.x; idx < total;
       idx += gridDim.y * blockDim.x) {
    int e   = idx & 7;
    int l15 = (idx >> 3) & 15;
    int lg  = (idx >> 7) & 3;
    int r   = idx >> 9;
    int ks  = r % KS;
    int nt  = r / KS;
    int n = nt * 16 + l15;
    int k = ks * 32 + lg * 8 + e;
    float v = 0.f;
    if (n < nc) {
      if (k < k1)       v = src[(o1 + k) * nc + n];
      else if (k >= k2) v = src[(k - k2) * nc + n];
    }
    dst[do_[c] + idx] = f2bf(v);
  }
}

// ---------------- posenc: 32 cols of one row, all indices compile-time ----------------
template<int I0, int L>
__device__ __forceinline__ void posenc_store(unsigned char* actb, int row,
                                             float p0, float p1, float p2)
{
#pragma unroll
  for (int q = 0; q < 4; q++) {
    float hv[8];
#pragma unroll
    for (int e = 0; e < 8; e++) {
      const int i = I0 + q * 8 + e;
      float v;
      if (i == 0) v = p0;
      else if (i == 1) v = p1;
      else if (i == 2) v = p2;
      else {
        const int idx = i - 3, j = idx / 6, t = idx % 6;
        if (j < L) {
          const float sc = (float)(1 << j);
          const float a  = (t % 3 == 0 ? p0 : (t % 3 == 1 ? p1 : p2)) * sc;
          v = (t < 3) ? __sinf(a) : __cosf(a);
        } else v = 0.f;
      }
      hv[e] = v;
    }
    uint4 pk;
    pk.x = pk2bf(hv[0], hv[1]);
    pk.y = pk2bf(hv[2], hv[3]);
    pk.z = pk2bf(hv[4], hv[5]);
    pk.w = pk2bf(hv[6], hv[7]);
    int b = (row * ROWB + (I0 + q * 8) * 2) ^ ((row & 7) << 4);
    *(uint4*)(actb + b) = pk;
  }
}

// ---------------- N-split layer: wave computes NTP output tiles for ALL 128 rows ----------------
// D[n][m] = sum_k Wt[n][k] * act[m][KB+k], n in [ntbase*16, (ntbase+NTP)*16)
// Inner-loop shape = R6's proven clean-allocation pattern: explicit acc init loop,
// afr array, accumulate-in-place (NO ks==0 peel -> no phi-induced scratch spill).
// MIDBAR: barrier between all-reads and writes (in-place layers). End barrier always.
// SIG: also accumulate sigma tile (chunk nt==8) for m-tiles {2*wid, 2*wid+1} -> out.
template<int KS, int NTP, int KB, int DST, bool RELU, bool MIDBAR, bool SIG>
__device__ __forceinline__ void layer_n(
    unsigned char* actb, const unsigned short* __restrict__ wchunk,
    int ntbase, int lane, int wid, float* __restrict__ out, long grow0)
{
  const int l15 = lane & 15;
  const int lg  = lane >> 4;
  const unsigned short* wl = wchunk + ntbase * (KS * 512) + lane * 8;
  const f32x4 vzero = {0.f, 0.f, 0.f, 0.f};
  f32x4 acc[8][NTP];
#pragma unroll
  for (int a = 0; a < 8; a++)
#pragma unroll
    for (int b = 0; b < NTP; b++) acc[a][b] = vzero;
  f32x4 accs[2];
  if (SIG) { accs[0] = vzero; accs[1] = vzero; }

#pragma unroll
  for (int ks = 0; ks < KS; ks++) {
    const int kloc = ks * 32 + lg * 8;
    bf16x8 afr[NTP];
#pragma unroll
    for (int nt = 0; nt < NTP; nt++)
      afr[nt] = *(const bf16x8*)(wl + (nt * KS + ks) * 512);
    bf16x8 bfr[8];
#pragma unroll
    for (int mt = 0; mt < 8; mt++) {
      int m = mt * 16 + l15;
      int byt = (m * ROWB + (KB + kloc) * 2) ^ ((m & 7) << 4);
      bfr[mt] = *(const bf16x8*)(actb + byt);
    }
#pragma unroll
    for (int nt = 0; nt < NTP; nt++)
#pragma unroll
      for (int mt = 0; mt < 8; mt++)
        acc[mt][nt] = __builtin_amdgcn_mfma_f32_16x16x32_bf16(
            afr[nt], bfr[mt], acc[mt][nt], 0, 0, 0);
    if (SIG) {   // sigma tile (chunk nt==8), m-tiles {2*wid, 2*wid+1}
      bf16x8 afs = *(const bf16x8*)(wchunk + (8 * KS + ks) * 512 + lane * 8);
#pragma unroll
      for (int j = 0; j < 2; j++) {
        int m = (2 * wid + j) * 16 + l15;
        int byt = (m * ROWB + (KB + kloc) * 2) ^ ((m & 7) << 4);
        bf16x8 bfs = *(const bf16x8*)(actb + byt);
        accs[j] = __builtin_amdgcn_mfma_f32_16x16x32_bf16(afs, bfs, accs[j], 0, 0, 0);
      }
    }
  }

  if (MIDBAR) __syncthreads();     // all reads of old act done before any write

#pragma unroll
  for (int mt = 0; mt < 8; mt++) {
    int m = mt * 16 + l15;
#pragma unroll
    for (int nt = 0; nt < NTP; nt++) {
      f32x4 v = acc[mt][nt];
      if (RELU) {
        v.x = fmaxf(v.x, 0.f); v.y = fmaxf(v.y, 0.f);
        v.z = fmaxf(v.z, 0.f); v.w = fmaxf(v.w, 0.f);
      }
      uint2 pk;
      pk.x = pk2bf(v.x, v.y);
      pk.y = pk2bf(v.z, v.w);
      int col = DST + (ntbase + nt) * 16 + lg * 4;
      int byt = (m * ROWB + col * 2) ^ ((m & 7) << 4);
      *(uint2*)(actb + byt) = pk;
    }
  }
  if (SIG && lg == 0) {
#pragma unroll
    for (int j = 0; j < 2; j++) {
      int m = (2 * wid + j) * 16 + l15;
      out[3L * NTOT + grow0 + m] = fmaxf(accs[j].x, 0.f);
    }
  }
  __syncthreads();                 // writes visible before next layer reads
}

// color: single n-tile, m-split {2*wid, 2*wid+1}; reads c1 cols 0..63; writes global only
__device__ __forceinline__ void color_n(
    unsigned char* actb, const unsigned short* __restrict__ wchunk,
    int lane, int wid, float* __restrict__ out, long grow0)
{
  const int l15 = lane & 15;
  const int lg  = lane >> 4;
  const f32x4 vzero = {0.f, 0.f, 0.f, 0.f};
  f32x4 acc[2];
  acc[0] = vzero; acc[1] = vzero;
#pragma unroll
  for (int ks = 0; ks < 2; ks++) {
    const int kloc = ks * 32 + lg * 8;
    bf16x8 afr = *(const bf16x8*)(wchunk + ks * 512 + lane * 8);
#pragma unroll
    for (int j = 0; j < 2; j++) {
      int m = (2 * wid + j) * 16 + l15;
      int byt = (m * ROWB + kloc * 2) ^ ((m & 7) << 4);
      bf16x8 bfr = *(const bf16x8*)(actb + byt);
      acc[j] = __builtin_amdgcn_mfma_f32_16x16x32_bf16(afr, bfr, acc[j], 0, 0, 0);
    }
  }
  if (lg == 0) {
#pragma unroll
    for (int j = 0; j < 2; j++) {
      int m = (2 * wid + j) * 16 + l15;
      long g3 = (grow0 + m) * 3;
      out[g3 + 0] = 1.f / (1.f + __expf(-acc[j].x));
      out[g3 + 1] = 1.f / (1.f + __expf(-acc[j].y));
      out[g3 + 2] = 1.f / (1.f + __expf(-acc[j].z));
    }
  }
}

__global__ __launch_bounds__(BLK, 3) void nerf_fused(
    const float* __restrict__ pos, const float* __restrict__ dirs,
    const unsigned short* __restrict__ wp, float* __restrict__ out)
{
  __shared__ unsigned char actb[ACT_BYTES];   // act[128][192] bf16, swizzled rows

  const int tid   = threadIdx.x;
  const int lane  = tid & 63;
  const int wid   = tid >> 6;
  const long grow0 = (long)blockIdx.x * MWG;

  const int row = wid * 32 + (lane & 31);
  const long g  = grow0 + row;

  // posenc(pos) -> cols 0..62 (col 63 = 0), own rows
  {
    float p0 = pos[g * 3 + 0], p1 = pos[g * 3 + 1], p2 = pos[g * 3 + 2];
    if (lane < 32) posenc_store<0, 10>(actb, row, p0, p1, p2);
    else           posenc_store<32, 10>(actb, row, p0, p1, p2);
  }
  __syncthreads();

  // b1_w0: reads cols 0..63, writes 64..191 (disjoint -> no midbar)
  layer_n<2, 2, 0, 64, true, false, false>(actb, wp +      0, wid*2, lane, wid, out, grow0);
  layer_n<4, 2, 64, 64, true, true, false>(actb, wp +   8192, wid*2, lane, wid, out, grow0); // b1_w1
  layer_n<4, 2, 64, 64, true, true, false>(actb, wp +  24576, wid*2, lane, wid, out, grow0); // b1_w2
  layer_n<4, 2, 64, 64, true, true, false>(actb, wp +  40960, wid*2, lane, wid, out, grow0); // b1_w3
  layer_n<4, 2, 64, 64, true, true, false>(actb, wp +  57344, wid*2, lane, wid, out, grow0); // b1_w4
  // b2_w0: K=192 reads 0..191, writes 64..191
  layer_n<6, 2, 0, 64, true, true, false>(actb, wp +  73728, wid*2, lane, wid, out, grow0);

  // posenc(dirs) -> cols 0..26 (27..63 zero), own rows; consumed only by b3_w0
  {
    float p0 = dirs[g * 3 + 0], p1 = dirs[g * 3 + 1], p2 = dirs[g * 3 + 2];
    if (lane < 32) posenc_store<0, 4>(actb, row, p0, p1, p2);
    else           posenc_store<32, 4>(actb, row, p0, p1, p2);   // all zeros
  }

  layer_n<4, 2, 64, 64, true, true, false>(actb, wp +  98304, wid*2, lane, wid, out, grow0); // b2_w1
  layer_n<4, 2, 64, 64, true, true, false>(actb, wp + 114688, wid*2, lane, wid, out, grow0); // b2_w2
  // b2_w3: feat (no relu) + sigma tile (SIG)
  layer_n<4, 2, 64, 64, false, true, true>(actb, wp + 131072, wid*2, lane, wid, out, grow0);
  // b3_w0: K=192 reads 0..191 (d_emb|feat), writes c1 cols 0..63
  layer_n<6, 1, 0, 0, true, true, false>(actb, wp + 149504, wid, lane, wid, out, grow0);
  // b3_w1 -> color (global only)
  color_n(actb, wp + 161792, lane, wid, out, grow0);
}

extern "C" void kernel_launch(void* const* d_in, const int* in_sizes, int n_in,
                              void* d_out, int out_size, void* d_ws, size_t ws_size,
                              hipStream_t stream)
{
  const float* pos  = (const float*)d_in[0];
  const float* dirs = (const float*)d_in[1];
  unsigned short* wpack = (unsigned short*)d_ws;   // 325,632 B used
  float* out = (float*)d_out;

  prepack_k<<<dim3(11, 12, 1), 256, 0, stream>>>(
      (const float*)d_in[2], (const float*)d_in[3], (const float*)d_in[4],
      (const float*)d_in[5], (const float*)d_in[6], (const float*)d_in[7],
      (const float*)d_in[8], (const float*)d_in[9], (const float*)d_in[10],
      (const float*)d_in[11], (const float*)d_in[12], wpack);

  nerf_fused<<<NTOT / MWG, BLK, 0, stream>>>(pos, dirs, wpack, out);
}

// Round 14
// 360.692 us; speedup vs baseline: 2.3907x; 1.4837x over previous
//
#include <hip/hip_runtime.h>
#include <hip/hip_bf16.h>

#define NTOT  1048576
#define MWG   128          // rows per workgroup
#define BLK   256          // threads (4 waves); N-split: wave w owns output tiles {2w,2w+1}
#define ROWB  384          // act row stride in bytes (192 bf16)
#define ACT_BYTES  (MWG * ROWB)          // 49152

typedef __attribute__((ext_vector_type(8))) short  bf16x8;
typedef __attribute__((ext_vector_type(4))) float  f32x4;

__device__ __forceinline__ unsigned short f2bf(float f) {
  unsigned u = __float_as_uint(f);
  u += 0x7fffu + ((u >> 16) & 1u);          // RNE
  return (unsigned short)(u >> 16);
}

__device__ __forceinline__ unsigned pk2bf(float lo, float hi) {
  float2 t; t.x = lo; t.y = hi;
  __hip_bfloat162 b = __float22bfloat162_rn(t);   // RNE
  return *(unsigned*)&b;
}

// ---------------- weight prepack (identical to R6/R13) ----------------
__global__ __launch_bounds__(256) void prepack_k(
    const float* __restrict__ s0, const float* __restrict__ s1,
    const float* __restrict__ s2, const float* __restrict__ s3,
    const float* __restrict__ s4, const float* __restrict__ s5,
    const float* __restrict__ s6, const float* __restrict__ s7,
    const float* __restrict__ s8, const float* __restrict__ s9,
    const float* __restrict__ s10, unsigned short* __restrict__ dst)
{
  const int nw_[11]  = {128,128,128,128,128,128,128,128,144, 64, 16};
  const int kw_[11]  = { 64,128,128,128,128,192,128,128,128,192, 64};
  const int nc_[11]  = {128,128,128,128,128,128,128,128,129, 64,  3};
  const int k1_[11]  = { 63,128,128,128,128, 63,128,128,128, 27, 64};
  const int o1_[11]  = {  0,  0,  0,  0,  0,128,  0,  0,  0,128,  0};
  const int k2_[11]  = {999,999,999,999,999, 64,999,999,999, 64,999};
  const int do_[11]  = {0,8192,24576,40960,57344,73728,98304,114688,131072,149504,161792};

  int c = blockIdx.x;
  const float* src =
    c==0?s0: c==1?s1: c==2?s2: c==3?s3: c==4?s4: c==5?s5:
    c==6?s6: c==7?s7: c==8?s8: c==9?s9: s10;
  int nw=nw_[c], kw=kw_[c], nc=nc_[c], k1=k1_[c], o1=o1_[c], k2=k2_[c];
  int KS = kw >> 5;
  int total = nw * kw;
  for (int idx = blockIdx.y * blockDim.x + threadIdx.x; idx < total;
       idx += gridDim.y * blockDim.x) {
    int e   = idx & 7;
    int l15 = (idx >> 3) & 15;
    int lg  = (idx >> 7) & 3;
    int r   = idx >> 9;
    int ks  = r % KS;
    int nt  = r / KS;
    int n = nt * 16 + l15;
    int k = ks * 32 + lg * 8 + e;
    float v = 0.f;
    if (n < nc) {
      if (k < k1)       v = src[(o1 + k) * nc + n];
      else if (k >= k2) v = src[(k - k2) * nc + n];
    }
    dst[do_[c] + idx] = f2bf(v);
  }
}

// ---------------- posenc: 32 cols of one row, all indices compile-time ----------------
template<int I0, int L>
__device__ __forceinline__ void posenc_store(unsigned char* actb, int row,
                                             float p0, float p1, float p2)
{
#pragma unroll
  for (int q = 0; q < 4; q++) {
    float hv[8];
#pragma unroll
    for (int e = 0; e < 8; e++) {
      const int i = I0 + q * 8 + e;
      float v;
      if (i == 0) v = p0;
      else if (i == 1) v = p1;
      else if (i == 2) v = p2;
      else {
        const int idx = i - 3, j = idx / 6, t = idx % 6;
        if (j < L) {
          const float sc = (float)(1 << j);
          const float a  = (t % 3 == 0 ? p0 : (t % 3 == 1 ? p1 : p2)) * sc;
          v = (t < 3) ? __sinf(a) : __cosf(a);
        } else v = 0.f;
      }
      hv[e] = v;
    }
    uint4 pk;
    pk.x = pk2bf(hv[0], hv[1]);
    pk.y = pk2bf(hv[2], hv[3]);
    pk.z = pk2bf(hv[4], hv[5]);
    pk.w = pk2bf(hv[6], hv[7]);
    int b = (row * ROWB + (I0 + q * 8) * 2) ^ ((row & 7) << 4);
    *(uint4*)(actb + b) = pk;
  }
}

// ---------------- N-split layer: wave computes NTP output tiles for ALL 128 rows ----------------
// D[n][m] = sum_k Wt[n][k] * act[m][KB+k], n in [ntbase*16, (ntbase+NTP)*16)
// bfr loaded in batches of 4 (peak frag liveness afr[NTP]+bfr4[4] ~ 24 regs).
// SIG (sigma tile) accumulated in a SEPARATE ks-loop after the main one (same
// pre-midbar LDS state -> correct; keeps main-loop pressure minimal).
template<int KS, int NTP, int KB, int DST, bool RELU, bool MIDBAR, bool SIG>
__device__ __forceinline__ void layer_n(
    unsigned char* actb, const unsigned short* __restrict__ wchunk,
    int ntbase, int lane, int wid, float* __restrict__ out, long grow0)
{
  const int l15 = lane & 15;
  const int lg  = lane >> 4;
  const unsigned short* wl = wchunk + ntbase * (KS * 512) + lane * 8;
  const f32x4 vzero = {0.f, 0.f, 0.f, 0.f};
  f32x4 acc[8][NTP];
#pragma unroll
  for (int a = 0; a < 8; a++)
#pragma unroll
    for (int b = 0; b < NTP; b++) acc[a][b] = vzero;

#pragma unroll
  for (int ks = 0; ks < KS; ks++) {
    const int kloc = ks * 32 + lg * 8;
    bf16x8 afr[NTP];
#pragma unroll
    for (int nt = 0; nt < NTP; nt++)
      afr[nt] = *(const bf16x8*)(wl + (nt * KS + ks) * 512);
#pragma unroll
    for (int half = 0; half < 2; half++) {
      bf16x8 bfr4[4];
#pragma unroll
      for (int mq = 0; mq < 4; mq++) {
        int m = (half * 4 + mq) * 16 + l15;
        int byt = (m * ROWB + (KB + kloc) * 2) ^ ((m & 7) << 4);
        bfr4[mq] = *(const bf16x8*)(actb + byt);
      }
#pragma unroll
      for (int nt = 0; nt < NTP; nt++)
#pragma unroll
        for (int mq = 0; mq < 4; mq++)
          acc[half * 4 + mq][nt] = __builtin_amdgcn_mfma_f32_16x16x32_bf16(
              afr[nt], bfr4[mq], acc[half * 4 + mq][nt], 0, 0, 0);
    }
  }

  f32x4 accs[2];
  if (SIG) {   // sigma tile (chunk nt==8), m-tiles {2*wid, 2*wid+1}; separate low-pressure loop
    accs[0] = vzero; accs[1] = vzero;
#pragma unroll
    for (int ks = 0; ks < KS; ks++) {
      const int kloc = ks * 32 + lg * 8;
      bf16x8 afs = *(const bf16x8*)(wchunk + (8 * KS + ks) * 512 + lane * 8);
#pragma unroll
      for (int j = 0; j < 2; j++) {
        int m = (2 * wid + j) * 16 + l15;
        int byt = (m * ROWB + (KB + kloc) * 2) ^ ((m & 7) << 4);
        bf16x8 bfs = *(const bf16x8*)(actb + byt);
        accs[j] = __builtin_amdgcn_mfma_f32_16x16x32_bf16(afs, bfs, accs[j], 0, 0, 0);
      }
    }
  }

  if (MIDBAR) __syncthreads();     // all reads of old act done before any write

#pragma unroll
  for (int mt = 0; mt < 8; mt++) {
    int m = mt * 16 + l15;
#pragma unroll
    for (int nt = 0; nt < NTP; nt++) {
      f32x4 v = acc[mt][nt];
      if (RELU) {
        v.x = fmaxf(v.x, 0.f); v.y = fmaxf(v.y, 0.f);
        v.z = fmaxf(v.z, 0.f); v.w = fmaxf(v.w, 0.f);
      }
      uint2 pk;
      pk.x = pk2bf(v.x, v.y);
      pk.y = pk2bf(v.z, v.w);
      int col = DST + (ntbase + nt) * 16 + lg * 4;
      int byt = (m * ROWB + col * 2) ^ ((m & 7) << 4);
      *(uint2*)(actb + byt) = pk;
    }
  }
  if (SIG && lg == 0) {
#pragma unroll
    for (int j = 0; j < 2; j++) {
      int m = (2 * wid + j) * 16 + l15;
      out[3L * NTOT + grow0 + m] = fmaxf(accs[j].x, 0.f);
    }
  }
  __syncthreads();                 // writes visible before next layer reads
}

// color: single n-tile, m-split {2*wid, 2*wid+1}; reads c1 cols 0..63; writes global only
__device__ __forceinline__ void color_n(
    unsigned char* actb, const unsigned short* __restrict__ wchunk,
    int lane, int wid, float* __restrict__ out, long grow0)
{
  const int l15 = lane & 15;
  const int lg  = lane >> 4;
  const f32x4 vzero = {0.f, 0.f, 0.f, 0.f};
  f32x4 acc[2];
  acc[0] = vzero; acc[1] = vzero;
#pragma unroll
  for (int ks = 0; ks < 2; ks++) {
    const int kloc = ks * 32 + lg * 8;
    bf16x8 afr = *(const bf16x8*)(wchunk + ks * 512 + lane * 8);
#pragma unroll
    for (int j = 0; j < 2; j++) {
      int m = (2 * wid + j) * 16 + l15;
      int byt = (m * ROWB + kloc * 2) ^ ((m & 7) << 4);
      bf16x8 bfr = *(const bf16x8*)(actb + byt);
      acc[j] = __builtin_amdgcn_mfma_f32_16x16x32_bf16(afr, bfr, acc[j], 0, 0, 0);
    }
  }
  if (lg == 0) {
#pragma unroll
    for (int j = 0; j < 2; j++) {
      int m = (2 * wid + j) * 16 + l15;
      long g3 = (grow0 + m) * 3;
      out[g3 + 0] = 1.f / (1.f + __expf(-acc[j].x));
      out[g3 + 1] = 1.f / (1.f + __expf(-acc[j].y));
      out[g3 + 2] = 1.f / (1.f + __expf(-acc[j].z));
    }
  }
}

__global__ __launch_bounds__(BLK, 3) void nerf_fused(
    const float* __restrict__ pos, const float* __restrict__ dirs,
    const unsigned short* __restrict__ wp, float* __restrict__ out)
{
  __shared__ unsigned char actb[ACT_BYTES];   // act[128][192] bf16, swizzled rows

  const int tid   = threadIdx.x;
  const int lane  = tid & 63;
  const int wid   = tid >> 6;
  const long grow0 = (long)blockIdx.x * MWG;

  const int row = wid * 32 + (lane & 31);
  const long g  = grow0 + row;

  // posenc(pos) -> cols 0..62 (col 63 = 0), own rows
  {
    float p0 = pos[g * 3 + 0], p1 = pos[g * 3 + 1], p2 = pos[g * 3 + 2];
    if (lane < 32) posenc_store<0, 10>(actb, row, p0, p1, p2);
    else           posenc_store<32, 10>(actb, row, p0, p1, p2);
  }
  __syncthreads();

  // b1_w0: reads cols 0..63, writes 64..191 (disjoint -> no midbar)
  layer_n<2, 2, 0, 64, true, false, false>(actb, wp +      0, wid*2, lane, wid, out, grow0);
  layer_n<4, 2, 64, 64, true, true, false>(actb, wp +   8192, wid*2, lane, wid, out, grow0); // b1_w1
  layer_n<4, 2, 64, 64, true, true, false>(actb, wp +  24576, wid*2, lane, wid, out, grow0); // b1_w2
  layer_n<4, 2, 64, 64, true, true, false>(actb, wp +  40960, wid*2, lane, wid, out, grow0); // b1_w3
  layer_n<4, 2, 64, 64, true, true, false>(actb, wp +  57344, wid*2, lane, wid, out, grow0); // b1_w4
  // b2_w0: K=192 reads 0..191, writes 64..191
  layer_n<6, 2, 0, 64, true, true, false>(actb, wp +  73728, wid*2, lane, wid, out, grow0);

  // posenc(dirs) -> cols 0..26 (27..63 zero), own rows; consumed only by b3_w0
  {
    float p0 = dirs[g * 3 + 0], p1 = dirs[g * 3 + 1], p2 = dirs[g * 3 + 2];
    if (lane < 32) posenc_store<0, 4>(actb, row, p0, p1, p2);
    else           posenc_store<32, 4>(actb, row, p0, p1, p2);   // all zeros
  }

  layer_n<4, 2, 64, 64, true, true, false>(actb, wp +  98304, wid*2, lane, wid, out, grow0); // b2_w1
  layer_n<4, 2, 64, 64, true, true, false>(actb, wp + 114688, wid*2, lane, wid, out, grow0); // b2_w2
  // b2_w3: feat (no relu) + sigma tile (SIG)
  layer_n<4, 2, 64, 64, false, true, true>(actb, wp + 131072, wid*2, lane, wid, out, grow0);
  // b3_w0: K=192 reads 0..191 (d_emb|feat), writes c1 cols 0..63
  layer_n<6, 1, 0, 0, true, true, false>(actb, wp + 149504, wid, lane, wid, out, grow0);
  // b3_w1 -> color (global only)
  color_n(actb, wp + 161792, lane, wid, out, grow0);
}

extern "C" void kernel_launch(void* const* d_in, const int* in_sizes, int n_in,
                              void* d_out, int out_size, void* d_ws, size_t ws_size,
                              hipStream_t stream)
{
  const float* pos  = (const float*)d_in[0];
  const float* dirs = (const float*)d_in[1];
  unsigned short* wpack = (unsigned short*)d_ws;   // 325,632 B used
  float* out = (float*)d_out;

  prepack_k<<<dim3(11, 12, 1), 256, 0, stream>>>(
      (const float*)d_in[2], (const float*)d_in[3], (const float*)d_in[4],
      (const float*)d_in[5], (const float*)d_in[6], (const float*)d_in[7],
      (const float*)d_in[8], (const float*)d_in[9], (const float*)d_in[10],
      (const float*)d_in[11], (const float*)d_in[12], wpack);

  nerf_fused<<<NTOT / MWG, BLK, 0, stream>>>(pos, dirs, wpack, out);
}

// Round 15
// 351.564 us; speedup vs baseline: 2.4527x; 1.0260x over previous
//
#include <hip/hip_runtime.h>
#include <hip/hip_bf16.h>

#define NTOT  1048576
#define MWG   128          // rows per workgroup
#define BLK   256          // threads (4 waves); N-split: wave w owns output tiles {2w,2w+1}
#define ROWB  384          // act row stride in bytes (192 bf16)
#define ACT_BYTES  (MWG * ROWB)          // 49152

typedef __attribute__((ext_vector_type(8))) short  bf16x8;
typedef __attribute__((ext_vector_type(4))) float  f32x4;

__device__ __forceinline__ unsigned short f2bf(float f) {
  unsigned u = __float_as_uint(f);
  u += 0x7fffu + ((u >> 16) & 1u);          // RNE
  return (unsigned short)(u >> 16);
}

__device__ __forceinline__ unsigned pk2bf(float lo, float hi) {
  float2 t; t.x = lo; t.y = hi;
  __hip_bfloat162 b = __float22bfloat162_rn(t);   // RNE
  return *(unsigned*)&b;
}

// ---------------- weight prepack (identical to R6/R13/R14) ----------------
__global__ __launch_bounds__(256) void prepack_k(
    const float* __restrict__ s0, const float* __restrict__ s1,
    const float* __restrict__ s2, const float* __restrict__ s3,
    const float* __restrict__ s4, const float* __restrict__ s5,
    const float* __restrict__ s6, const float* __restrict__ s7,
    const float* __restrict__ s8, const float* __restrict__ s9,
    const float* __restrict__ s10, unsigned short* __restrict__ dst)
{
  const int nw_[11]  = {128,128,128,128,128,128,128,128,144, 64, 16};
  const int kw_[11]  = { 64,128,128,128,128,192,128,128,128,192, 64};
  const int nc_[11]  = {128,128,128,128,128,128,128,128,129, 64,  3};
  const int k1_[11]  = { 63,128,128,128,128, 63,128,128,128, 27, 64};
  const int o1_[11]  = {  0,  0,  0,  0,  0,128,  0,  0,  0,128,  0};
  const int k2_[11]  = {999,999,999,999,999, 64,999,999,999, 64,999};
  const int do_[11]  = {0,8192,24576,40960,57344,73728,98304,114688,131072,149504,161792};

  int c = blockIdx.x;
  const float* src =
    c==0?s0: c==1?s1: c==2?s2: c==3?s3: c==4?s4: c==5?s5:
    c==6?s6: c==7?s7: c==8?s8: c==9?s9: s10;
  int nw=nw_[c], kw=kw_[c], nc=nc_[c], k1=k1_[c], o1=o1_[c], k2=k2_[c];
  int KS = kw >> 5;
  int total = nw * kw;
  for (int idx = blockIdx.y * blockDim.x + threadIdx.x; idx < total;
       idx += gridDim.y * blockDim.x) {
    int e   = idx & 7;
    int l15 = (idx >> 3) & 15;
    int lg  = (idx >> 7) & 3;
    int r   = idx >> 9;
    int ks  = r % KS;
    int nt  = r / KS;
    int n = nt * 16 + l15;
    int k = ks * 32 + lg * 8 + e;
    float v = 0.f;
    if (n < nc) {
      if (k < k1)       v = src[(o1 + k) * nc + n];
      else if (k >= k2) v = src[(k - k2) * nc + n];
    }
    dst[do_[c] + idx] = f2bf(v);
  }
}

// ---------------- posenc: 32 cols of one row, all indices compile-time ----------------
template<int I0, int L>
__device__ __forceinline__ void posenc_store(unsigned char* actb, int row,
                                             float p0, float p1, float p2)
{
#pragma unroll
  for (int q = 0; q < 4; q++) {
    float hv[8];
#pragma unroll
    for (int e = 0; e < 8; e++) {
      const int i = I0 + q * 8 + e;
      float v;
      if (i == 0) v = p0;
      else if (i == 1) v = p1;
      else if (i == 2) v = p2;
      else {
        const int idx = i - 3, j = idx / 6, t = idx % 6;
        if (j < L) {
          const float sc = (float)(1 << j);
          const float a  = (t % 3 == 0 ? p0 : (t % 3 == 1 ? p1 : p2)) * sc;
          v = (t < 3) ? __sinf(a) : __cosf(a);
        } else v = 0.f;
      }
      hv[e] = v;
    }
    uint4 pk;
    pk.x = pk2bf(hv[0], hv[1]);
    pk.y = pk2bf(hv[2], hv[3]);
    pk.z = pk2bf(hv[4], hv[5]);
    pk.w = pk2bf(hv[6], hv[7]);
    int b = (row * ROWB + (I0 + q * 8) * 2) ^ ((row & 7) << 4);
    *(uint4*)(actb + b) = pk;
  }
}

// ---------------- N-split layer: wave computes NTP output tiles for ALL 128 rows ----------------
// D[n][m] = sum_k Wt[n][k] * act[m][KB+k], n in [ntbase*16, (ntbase+NTP)*16)
// bfr loaded in batches of 4; SIG in separate low-pressure loop (pre-midbar state).
template<int KS, int NTP, int KB, int DST, bool RELU, bool MIDBAR, bool SIG>
__device__ __forceinline__ void layer_n(
    unsigned char* actb, const unsigned short* __restrict__ wchunk,
    int ntbase, int lane, int wid, float* __restrict__ out, long grow0)
{
  const int l15 = lane & 15;
  const int lg  = lane >> 4;
  const unsigned short* wl = wchunk + ntbase * (KS * 512) + lane * 8;
  const f32x4 vzero = {0.f, 0.f, 0.f, 0.f};
  f32x4 acc[8][NTP];
#pragma unroll
  for (int a = 0; a < 8; a++)
#pragma unroll
    for (int b = 0; b < NTP; b++) acc[a][b] = vzero;

#pragma unroll
  for (int ks = 0; ks < KS; ks++) {
    const int kloc = ks * 32 + lg * 8;
    bf16x8 afr[NTP];
#pragma unroll
    for (int nt = 0; nt < NTP; nt++)
      afr[nt] = *(const bf16x8*)(wl + (nt * KS + ks) * 512);
#pragma unroll
    for (int half = 0; half < 2; half++) {
      bf16x8 bfr4[4];
#pragma unroll
      for (int mq = 0; mq < 4; mq++) {
        int m = (half * 4 + mq) * 16 + l15;
        int byt = (m * ROWB + (KB + kloc) * 2) ^ ((m & 7) << 4);
        bfr4[mq] = *(const bf16x8*)(actb + byt);
      }
#pragma unroll
      for (int nt = 0; nt < NTP; nt++)
#pragma unroll
        for (int mq = 0; mq < 4; mq++)
          acc[half * 4 + mq][nt] = __builtin_amdgcn_mfma_f32_16x16x32_bf16(
              afr[nt], bfr4[mq], acc[half * 4 + mq][nt], 0, 0, 0);
    }
  }

  f32x4 accs[2];
  if (SIG) {   // sigma tile (chunk nt==8), m-tiles {2*wid, 2*wid+1}; separate low-pressure loop
    accs[0] = vzero; accs[1] = vzero;
#pragma unroll
    for (int ks = 0; ks < KS; ks++) {
      const int kloc = ks * 32 + lg * 8;
      bf16x8 afs = *(const bf16x8*)(wchunk + (8 * KS + ks) * 512 + lane * 8);
#pragma unroll
      for (int j = 0; j < 2; j++) {
        int m = (2 * wid + j) * 16 + l15;
        int byt = (m * ROWB + (KB + kloc) * 2) ^ ((m & 7) << 4);
        bf16x8 bfs = *(const bf16x8*)(actb + byt);
        accs[j] = __builtin_amdgcn_mfma_f32_16x16x32_bf16(afs, bfs, accs[j], 0, 0, 0);
      }
    }
  }

  if (MIDBAR) __syncthreads();     // all reads of old act done before any write

#pragma unroll
  for (int mt = 0; mt < 8; mt++) {
    int m = mt * 16 + l15;
#pragma unroll
    for (int nt = 0; nt < NTP; nt++) {
      f32x4 v = acc[mt][nt];
      if (RELU) {
        v.x = fmaxf(v.x, 0.f); v.y = fmaxf(v.y, 0.f);
        v.z = fmaxf(v.z, 0.f); v.w = fmaxf(v.w, 0.f);
      }
      uint2 pk;
      pk.x = pk2bf(v.x, v.y);
      pk.y = pk2bf(v.z, v.w);
      int col = DST + (ntbase + nt) * 16 + lg * 4;
      int byt = (m * ROWB + col * 2) ^ ((m & 7) << 4);
      *(uint2*)(actb + byt) = pk;
    }
  }
  if (SIG && lg == 0) {
#pragma unroll
    for (int j = 0; j < 2; j++) {
      int m = (2 * wid + j) * 16 + l15;
      out[3L * NTOT + grow0 + m] = fmaxf(accs[j].x, 0.f);
    }
  }
  __syncthreads();                 // writes visible before next layer reads
}

// color: single n-tile, m-split {2*wid, 2*wid+1}; reads c1 cols 0..63; writes global only
__device__ __forceinline__ void color_n(
    unsigned char* actb, const unsigned short* __restrict__ wchunk,
    int lane, int wid, float* __restrict__ out, long grow0)
{
  const int l15 = lane & 15;
  const int lg  = lane >> 4;
  const f32x4 vzero = {0.f, 0.f, 0.f, 0.f};
  f32x4 acc[2];
  acc[0] = vzero; acc[1] = vzero;
#pragma unroll
  for (int ks = 0; ks < 2; ks++) {
    const int kloc = ks * 32 + lg * 8;
    bf16x8 afr = *(const bf16x8*)(wchunk + ks * 512 + lane * 8);
#pragma unroll
    for (int j = 0; j < 2; j++) {
      int m = (2 * wid + j) * 16 + l15;
      int byt = (m * ROWB + kloc * 2) ^ ((m & 7) << 4);
      bf16x8 bfr = *(const bf16x8*)(actb + byt);
      acc[j] = __builtin_amdgcn_mfma_f32_16x16x32_bf16(afr, bfr, acc[j], 0, 0, 0);
    }
  }
  if (lg == 0) {
#pragma unroll
    for (int j = 0; j < 2; j++) {
      int m = (2 * wid + j) * 16 + l15;
      long g3 = (grow0 + m) * 3;
      out[g3 + 0] = 1.f / (1.f + __expf(-acc[j].x));
      out[g3 + 1] = 1.f / (1.f + __expf(-acc[j].y));
      out[g3 + 2] = 1.f / (1.f + __expf(-acc[j].z));
    }
  }
}

__global__ __launch_bounds__(BLK, 2) void nerf_fused(
    const float* __restrict__ pos, const float* __restrict__ dirs,
    const unsigned short* __restrict__ wp, float* __restrict__ out)
{
  __shared__ unsigned char actb[ACT_BYTES];   // act[128][192] bf16, swizzled rows

  const int tid   = threadIdx.x;
  const int lane  = tid & 63;
  const int wid   = tid >> 6;
  const long grow0 = (long)blockIdx.x * MWG;

  const int row = wid * 32 + (lane & 31);
  const long g  = grow0 + row;

  // posenc(pos) -> cols 0..62 (col 63 = 0), own rows
  {
    float p0 = pos[g * 3 + 0], p1 = pos[g * 3 + 1], p2 = pos[g * 3 + 2];
    if (lane < 32) posenc_store<0, 10>(actb, row, p0, p1, p2);
    else           posenc_store<32, 10>(actb, row, p0, p1, p2);
  }
  __syncthreads();

  // b1_w0: reads cols 0..63, writes 64..191 (disjoint -> no midbar)
  layer_n<2, 2, 0, 64, true, false, false>(actb, wp +      0, wid*2, lane, wid, out, grow0);
  layer_n<4, 2, 64, 64, true, true, false>(actb, wp +   8192, wid*2, lane, wid, out, grow0); // b1_w1
  layer_n<4, 2, 64, 64, true, true, false>(actb, wp +  24576, wid*2, lane, wid, out, grow0); // b1_w2
  layer_n<4, 2, 64, 64, true, true, false>(actb, wp +  40960, wid*2, lane, wid, out, grow0); // b1_w3
  layer_n<4, 2, 64, 64, true, true, false>(actb, wp +  57344, wid*2, lane, wid, out, grow0); // b1_w4
  // b2_w0: K=192 reads 0..191, writes 64..191
  layer_n<6, 2, 0, 64, true, true, false>(actb, wp +  73728, wid*2, lane, wid, out, grow0);

  // posenc(dirs) -> cols 0..26 (27..63 zero), own rows; consumed only by b3_w0
  {
    float p0 = dirs[g * 3 + 0], p1 = dirs[g * 3 + 1], p2 = dirs[g * 3 + 2];
    if (lane < 32) posenc_store<0, 4>(actb, row, p0, p1, p2);
    else           posenc_store<32, 4>(actb, row, p0, p1, p2);   // all zeros
  }

  layer_n<4, 2, 64, 64, true, true, false>(actb, wp +  98304, wid*2, lane, wid, out, grow0); // b2_w1
  layer_n<4, 2, 64, 64, true, true, false>(actb, wp + 114688, wid*2, lane, wid, out, grow0); // b2_w2
  // b2_w3: feat (no relu) + sigma tile (SIG)
  layer_n<4, 2, 64, 64, false, true, true>(actb, wp + 131072, wid*2, lane, wid, out, grow0);
  // b3_w0: K=192 reads 0..191 (d_emb|feat), writes c1 cols 0..63
  layer_n<6, 1, 0, 0, true, true, false>(actb, wp + 149504, wid, lane, wid, out, grow0);
  // b3_w1 -> color (global only)
  color_n(actb, wp + 161792, lane, wid, out, grow0);
}

extern "C" void kernel_launch(void* const* d_in, const int* in_sizes, int n_in,
                              void* d_out, int out_size, void* d_ws, size_t ws_size,
                              hipStream_t stream)
{
  const float* pos  = (const float*)d_in[0];
  const float* dirs = (const float*)d_in[1];
  unsigned short* wpack = (unsigned short*)d_ws;   // 325,632 B used
  float* out = (float*)d_out;

  prepack_k<<<dim3(11, 12, 1), 256, 0, stream>>>(
      (const float*)d_in[2], (const float*)d_in[3], (const float*)d_in[4],
      (const float*)d_in[5], (const float*)d_in[6], (const float*)d_in[7],
      (const float*)d_in[8], (const float*)d_in[9], (const float*)d_in[10],
      (const float*)d_in[11], (const float*)d_in[12], wpack);

  nerf_fused<<<NTOT / MWG, BLK, 0, stream>>>(pos, dirs, wpack, out);
}

// Round 16
// 349.002 us; speedup vs baseline: 2.4708x; 1.0073x over previous
//
#include <hip/hip_runtime.h>
#include <hip/hip_bf16.h>

#define NTOT  1048576
#define MWG   128          // rows per workgroup
#define BLK   256          // 4 waves in 2x2: wave (wm,wn) owns rows [wm*64,+64) x ntiles [wn*4,+4)
#define ROWB  384          // act row stride in bytes (192 bf16)
#define ACT_BYTES  (MWG * ROWB)          // 49152

typedef __attribute__((ext_vector_type(8))) short  bf16x8;
typedef __attribute__((ext_vector_type(4))) float  f32x4;

__device__ __forceinline__ unsigned short f2bf(float f) {
  unsigned u = __float_as_uint(f);
  u += 0x7fffu + ((u >> 16) & 1u);          // RNE
  return (unsigned short)(u >> 16);
}

__device__ __forceinline__ unsigned pk2bf(float lo, float hi) {
  float2 t; t.x = lo; t.y = hi;
  __hip_bfloat162 b = __float22bfloat162_rn(t);   // RNE
  return *(unsigned*)&b;
}

// ---------------- weight prepack (identical to R6..R15) ----------------
__global__ __launch_bounds__(256) void prepack_k(
    const float* __restrict__ s0, const float* __restrict__ s1,
    const float* __restrict__ s2, const float* __restrict__ s3,
    const float* __restrict__ s4, const float* __restrict__ s5,
    const float* __restrict__ s6, const float* __restrict__ s7,
    const float* __restrict__ s8, const float* __restrict__ s9,
    const float* __restrict__ s10, unsigned short* __restrict__ dst)
{
  const int nw_[11]  = {128,128,128,128,128,128,128,128,144, 64, 16};
  const int kw_[11]  = { 64,128,128,128,128,192,128,128,128,192, 64};
  const int nc_[11]  = {128,128,128,128,128,128,128,128,129, 64,  3};
  const int k1_[11]  = { 63,128,128,128,128, 63,128,128,128, 27, 64};
  const int o1_[11]  = {  0,  0,  0,  0,  0,128,  0,  0,  0,128,  0};
  const int k2_[11]  = {999,999,999,999,999, 64,999,999,999, 64,999};
  const int do_[11]  = {0,8192,24576,40960,57344,73728,98304,114688,131072,149504,161792};

  int c = blockIdx.x;
  const float* src =
    c==0?s0: c==1?s1: c==2?s2: c==3?s3: c==4?s4: c==5?s5:
    c==6?s6: c==7?s7: c==8?s8: c==9?s9: s10;
  int nw=nw_[c], kw=kw_[c], nc=nc_[c], k1=k1_[c], o1=o1_[c], k2=k2_[c];
  int KS = kw >> 5;
  int total = nw * kw;
  for (int idx = blockIdx.y * blockDim.x + threadIdx.x; idx < total;
       idx += gridDim.y * blockDim.x) {
    int e   = idx & 7;
    int l15 = (idx >> 3) & 15;
    int lg  = (idx >> 7) & 3;
    int r   = idx >> 9;
    int ks  = r % KS;
    int nt  = r / KS;
    int n = nt * 16 + l15;
    int k = ks * 32 + lg * 8 + e;
    float v = 0.f;
    if (n < nc) {
      if (k < k1)       v = src[(o1 + k) * nc + n];
      else if (k >= k2) v = src[(k - k2) * nc + n];
    }
    dst[do_[c] + idx] = f2bf(v);
  }
}

// ---------------- posenc: 32 cols of one row, all indices compile-time ----------------
template<int I0, int L>
__device__ __forceinline__ void posenc_store(unsigned char* actb, int row,
                                             float p0, float p1, float p2)
{
#pragma unroll
  for (int q = 0; q < 4; q++) {
    float hv[8];
#pragma unroll
    for (int e = 0; e < 8; e++) {
      const int i = I0 + q * 8 + e;
      float v;
      if (i == 0) v = p0;
      else if (i == 1) v = p1;
      else if (i == 2) v = p2;
      else {
        const int idx = i - 3, j = idx / 6, t = idx % 6;
        if (j < L) {
          const float sc = (float)(1 << j);
          const float a  = (t % 3 == 0 ? p0 : (t % 3 == 1 ? p1 : p2)) * sc;
          v = (t < 3) ? __sinf(a) : __cosf(a);
        } else v = 0.f;
      }
      hv[e] = v;
    }
    uint4 pk;
    pk.x = pk2bf(hv[0], hv[1]);
    pk.y = pk2bf(hv[2], hv[3]);
    pk.z = pk2bf(hv[4], hv[5]);
    pk.w = pk2bf(hv[6], hv[7]);
    int b = (row * ROWB + (I0 + q * 8) * 2) ^ ((row & 7) << 4);
    *(uint4*)(actb + b) = pk;
  }
}

// ---------------- 2x2 tile layer: wave (wm,wn) computes rows [wm*64,+64) x ntiles [wn*4,+4) ----------------
// D[n][m] = sum_k Wt[n][k] * act[m][KB+k].  Each wave reads only its own 64 rows (half the
// LDS traffic of full-row N-split); weight tiles shared by the 2 waves with equal wn (L1 reuse).
// SIG: sigma tile (chunk nt==8) for m-tiles {2*wid, 2*wid+1} in a separate low-pressure loop.
template<int KS, int NTP, int KB, int DST, bool RELU, bool MIDBAR, bool SIG>
__device__ __forceinline__ void layer22(
    unsigned char* actb, const unsigned short* __restrict__ wchunk,
    int lane, int wm, int wn, int wid, float* __restrict__ out, long grow0)
{
  const int l15 = lane & 15;
  const int lg  = lane >> 4;
  const unsigned short* wl = wchunk + (wn * 4) * (KS * 512) + lane * 8;
  const f32x4 vzero = {0.f, 0.f, 0.f, 0.f};
  f32x4 acc[4][NTP];
#pragma unroll
  for (int a = 0; a < 4; a++)
#pragma unroll
    for (int b = 0; b < NTP; b++) acc[a][b] = vzero;

#pragma unroll
  for (int ks = 0; ks < KS; ks++) {
    const int kloc = ks * 32 + lg * 8;
    bf16x8 afr[NTP];
#pragma unroll
    for (int nt = 0; nt < NTP; nt++)
      afr[nt] = *(const bf16x8*)(wl + (nt * KS + ks) * 512);
    bf16x8 bfr4[4];
#pragma unroll
    for (int mq = 0; mq < 4; mq++) {
      int m = wm * 64 + mq * 16 + l15;
      int byt = (m * ROWB + (KB + kloc) * 2) ^ ((m & 7) << 4);
      bfr4[mq] = *(const bf16x8*)(actb + byt);
    }
#pragma unroll
    for (int nt = 0; nt < NTP; nt++)
#pragma unroll
      for (int mq = 0; mq < 4; mq++)
        acc[mq][nt] = __builtin_amdgcn_mfma_f32_16x16x32_bf16(
            afr[nt], bfr4[mq], acc[mq][nt], 0, 0, 0);
  }

  f32x4 accs[2];
  if (SIG) {   // sigma tile (chunk nt==8), m-tiles {2*wid, 2*wid+1}; separate low-pressure loop
    accs[0] = vzero; accs[1] = vzero;
#pragma unroll
    for (int ks = 0; ks < KS; ks++) {
      const int kloc = ks * 32 + lg * 8;
      bf16x8 afs = *(const bf16x8*)(wchunk + (8 * KS + ks) * 512 + lane * 8);
#pragma unroll
      for (int j = 0; j < 2; j++) {
        int m = (2 * wid + j) * 16 + l15;
        int byt = (m * ROWB + (KB + kloc) * 2) ^ ((m & 7) << 4);
        bf16x8 bfs = *(const bf16x8*)(actb + byt);
        accs[j] = __builtin_amdgcn_mfma_f32_16x16x32_bf16(afs, bfs, accs[j], 0, 0, 0);
      }
    }
  }

  if (MIDBAR) __syncthreads();     // all reads of old act done before any write

#pragma unroll
  for (int mq = 0; mq < 4; mq++) {
    int m = wm * 64 + mq * 16 + l15;
#pragma unroll
    for (int nt = 0; nt < NTP; nt++) {
      f32x4 v = acc[mq][nt];
      if (RELU) {
        v.x = fmaxf(v.x, 0.f); v.y = fmaxf(v.y, 0.f);
        v.z = fmaxf(v.z, 0.f); v.w = fmaxf(v.w, 0.f);
      }
      uint2 pk;
      pk.x = pk2bf(v.x, v.y);
      pk.y = pk2bf(v.z, v.w);
      int col = DST + (wn * 4 + nt) * 16 + lg * 4;
      int byt = (m * ROWB + col * 2) ^ ((m & 7) << 4);
      *(uint2*)(actb + byt) = pk;
    }
  }
  if (SIG && lg == 0) {
#pragma unroll
    for (int j = 0; j < 2; j++) {
      int m = (2 * wid + j) * 16 + l15;
      out[3L * NTOT + grow0 + m] = fmaxf(accs[j].x, 0.f);
    }
  }
  __syncthreads();                 // writes visible before next layer reads
}

// ---------------- full-row N-split layer (for b3_w0: 64 outputs, NTP=1 per wave) ----------------
template<int KS, int NTP, int KB, int DST, bool RELU, bool MIDBAR>
__device__ __forceinline__ void layer_n(
    unsigned char* actb, const unsigned short* __restrict__ wchunk,
    int ntbase, int lane)
{
  const int l15 = lane & 15;
  const int lg  = lane >> 4;
  const unsigned short* wl = wchunk + ntbase * (KS * 512) + lane * 8;
  const f32x4 vzero = {0.f, 0.f, 0.f, 0.f};
  f32x4 acc[8][NTP];
#pragma unroll
  for (int a = 0; a < 8; a++)
#pragma unroll
    for (int b = 0; b < NTP; b++) acc[a][b] = vzero;

#pragma unroll
  for (int ks = 0; ks < KS; ks++) {
    const int kloc = ks * 32 + lg * 8;
    bf16x8 afr[NTP];
#pragma unroll
    for (int nt = 0; nt < NTP; nt++)
      afr[nt] = *(const bf16x8*)(wl + (nt * KS + ks) * 512);
#pragma unroll
    for (int half = 0; half < 2; half++) {
      bf16x8 bfr4[4];
#pragma unroll
      for (int mq = 0; mq < 4; mq++) {
        int m = (half * 4 + mq) * 16 + l15;
        int byt = (m * ROWB + (KB + kloc) * 2) ^ ((m & 7) << 4);
        bfr4[mq] = *(const bf16x8*)(actb + byt);
      }
#pragma unroll
      for (int nt = 0; nt < NTP; nt++)
#pragma unroll
        for (int mq = 0; mq < 4; mq++)
          acc[half * 4 + mq][nt] = __builtin_amdgcn_mfma_f32_16x16x32_bf16(
              afr[nt], bfr4[mq], acc[half * 4 + mq][nt], 0, 0, 0);
    }
  }

  if (MIDBAR) __syncthreads();

#pragma unroll
  for (int mt = 0; mt < 8; mt++) {
    int m = mt * 16 + l15;
#pragma unroll
    for (int nt = 0; nt < NTP; nt++) {
      f32x4 v = acc[mt][nt];
      if (RELU) {
        v.x = fmaxf(v.x, 0.f); v.y = fmaxf(v.y, 0.f);
        v.z = fmaxf(v.z, 0.f); v.w = fmaxf(v.w, 0.f);
      }
      uint2 pk;
      pk.x = pk2bf(v.x, v.y);
      pk.y = pk2bf(v.z, v.w);
      int col = DST + (ntbase + nt) * 16 + lg * 4;
      int byt = (m * ROWB + col * 2) ^ ((m & 7) << 4);
      *(uint2*)(actb + byt) = pk;
    }
  }
  __syncthreads();
}

// color: single n-tile, m-split {2*wid, 2*wid+1}; reads c1 cols 0..63; writes global only
__device__ __forceinline__ void color_n(
    unsigned char* actb, const unsigned short* __restrict__ wchunk,
    int lane, int wid, float* __restrict__ out, long grow0)
{
  const int l15 = lane & 15;
  const int lg  = lane >> 4;
  const f32x4 vzero = {0.f, 0.f, 0.f, 0.f};
  f32x4 acc[2];
  acc[0] = vzero; acc[1] = vzero;
#pragma unroll
  for (int ks = 0; ks < 2; ks++) {
    const int kloc = ks * 32 + lg * 8;
    bf16x8 afr = *(const bf16x8*)(wchunk + ks * 512 + lane * 8);
#pragma unroll
    for (int j = 0; j < 2; j++) {
      int m = (2 * wid + j) * 16 + l15;
      int byt = (m * ROWB + kloc * 2) ^ ((m & 7) << 4);
      bf16x8 bfr = *(const bf16x8*)(actb + byt);
      acc[j] = __builtin_amdgcn_mfma_f32_16x16x32_bf16(afr, bfr, acc[j], 0, 0, 0);
    }
  }
  if (lg == 0) {
#pragma unroll
    for (int j = 0; j < 2; j++) {
      int m = (2 * wid + j) * 16 + l15;
      long g3 = (grow0 + m) * 3;
      out[g3 + 0] = 1.f / (1.f + __expf(-acc[j].x));
      out[g3 + 1] = 1.f / (1.f + __expf(-acc[j].y));
      out[g3 + 2] = 1.f / (1.f + __expf(-acc[j].z));
    }
  }
}

__global__ __launch_bounds__(BLK, 2) void nerf_fused(
    const float* __restrict__ pos, const float* __restrict__ dirs,
    const unsigned short* __restrict__ wp, float* __restrict__ out)
{
  __shared__ unsigned char actb[ACT_BYTES];   // act[128][192] bf16, swizzled rows

  const int tid   = threadIdx.x;
  const int lane  = tid & 63;
  const int wid   = tid >> 6;
  const int wm    = wid >> 1;                 // row half
  const int wn    = wid & 1;                  // col half
  const long grow0 = (long)blockIdx.x * MWG;

  const int row = wid * 32 + (lane & 31);
  const long g  = grow0 + row;

  // posenc(pos) -> cols 0..62 (col 63 = 0), own rows
  {
    float p0 = pos[g * 3 + 0], p1 = pos[g * 3 + 1], p2 = pos[g * 3 + 2];
    if (lane < 32) posenc_store<0, 10>(actb, row, p0, p1, p2);
    else           posenc_store<32, 10>(actb, row, p0, p1, p2);
  }
  __syncthreads();

  // b1_w0: reads cols 0..63, writes 64..191 (disjoint -> no midbar)
  layer22<2, 4, 0, 64, true, false, false>(actb, wp +      0, lane, wm, wn, wid, out, grow0);
  layer22<4, 4, 64, 64, true, true, false>(actb, wp +   8192, lane, wm, wn, wid, out, grow0); // b1_w1
  layer22<4, 4, 64, 64, true, true, false>(actb, wp +  24576, lane, wm, wn, wid, out, grow0); // b1_w2
  layer22<4, 4, 64, 64, true, true, false>(actb, wp +  40960, lane, wm, wn, wid, out, grow0); // b1_w3
  layer22<4, 4, 64, 64, true, true, false>(actb, wp +  57344, lane, wm, wn, wid, out, grow0); // b1_w4
  // b2_w0: K=192 reads 0..191, writes 64..191
  layer22<6, 4, 0, 64, true, true, false>(actb, wp +  73728, lane, wm, wn, wid, out, grow0);

  // posenc(dirs) -> cols 0..26 (27..63 zero), own rows; consumed only by b3_w0 (after barriers)
  {
    float p0 = dirs[g * 3 + 0], p1 = dirs[g * 3 + 1], p2 = dirs[g * 3 + 2];
    if (lane < 32) posenc_store<0, 4>(actb, row, p0, p1, p2);
    else           posenc_store<32, 4>(actb, row, p0, p1, p2);   // all zeros
  }

  layer22<4, 4, 64, 64, true, true, false>(actb, wp +  98304, lane, wm, wn, wid, out, grow0); // b2_w1
  layer22<4, 4, 64, 64, true, true, false>(actb, wp + 114688, lane, wm, wn, wid, out, grow0); // b2_w2
  // b2_w3: feat (no relu) + sigma tile (SIG)
  layer22<4, 4, 64, 64, false, true, true>(actb, wp + 131072, lane, wm, wn, wid, out, grow0);
  // b3_w0: K=192 reads 0..191 (d_emb|feat), writes c1 cols 0..63 (full-row N-split, NTP=1/wave)
  layer_n<6, 1, 0, 0, true, true>(actb, wp + 149504, wid, lane);
  // b3_w1 -> color (global only)
  color_n(actb, wp + 161792, lane, wid, out, grow0);
}

extern "C" void kernel_launch(void* const* d_in, const int* in_sizes, int n_in,
                              void* d_out, int out_size, void* d_ws, size_t ws_size,
                              hipStream_t stream)
{
  const float* pos  = (const float*)d_in[0];
  const float* dirs = (const float*)d_in[1];
  unsigned short* wpack = (unsigned short*)d_ws;   // 325,632 B used
  float* out = (float*)d_out;

  prepack_k<<<dim3(11, 12, 1), 256, 0, stream>>>(
      (const float*)d_in[2], (const float*)d_in[3], (const float*)d_in[4],
      (const float*)d_in[5], (const float*)d_in[6], (const float*)d_in[7],
      (const float*)d_in[8], (const float*)d_in[9], (const float*)d_in[10],
      (const float*)d_in[11], (const float*)d_in[12], wpack);

  nerf_fused<<<NTOT / MWG, BLK, 0, stream>>>(pos, dirs, wpack, out);
}

// Round 17
// 332.457 us; speedup vs baseline: 2.5937x; 1.0498x over previous
//
#include <hip/hip_runtime.h>
#include <hip/hip_bf16.h>

#define NTOT  1048576
#define MWG   128          // rows per workgroup
#define BLK   256          // 4 waves in 2x2: wave (wm,wn) owns rows [wm*64,+64) x ntiles [wn*4,+4)
#define ROWB  400          // act row stride bytes (192 bf16 + 16B pad): 100 dwords = 4 mod 32 banks
                           // -> 2-way bank aliasing WITHOUT swizzle; all LDS addrs = base + imm
#define ACT_BYTES  (MWG * ROWB)          // 51200; x3 blocks = 150 KB <= 160 KB

typedef __attribute__((ext_vector_type(8))) short  bf16x8;
typedef __attribute__((ext_vector_type(4))) float  f32x4;

__device__ __forceinline__ unsigned short f2bf(float f) {
  unsigned u = __float_as_uint(f);
  u += 0x7fffu + ((u >> 16) & 1u);          // RNE
  return (unsigned short)(u >> 16);
}

__device__ __forceinline__ unsigned pk2bf(float lo, float hi) {
  float2 t; t.x = lo; t.y = hi;
  __hip_bfloat162 b = __float22bfloat162_rn(t);   // RNE
  return *(unsigned*)&b;
}

// ---------------- weight prepack (identical to R6..R16) ----------------
__global__ __launch_bounds__(256) void prepack_k(
    const float* __restrict__ s0, const float* __restrict__ s1,
    const float* __restrict__ s2, const float* __restrict__ s3,
    const float* __restrict__ s4, const float* __restrict__ s5,
    const float* __restrict__ s6, const float* __restrict__ s7,
    const float* __restrict__ s8, const float* __restrict__ s9,
    const float* __restrict__ s10, unsigned short* __restrict__ dst)
{
  const int nw_[11]  = {128,128,128,128,128,128,128,128,144, 64, 16};
  const int kw_[11]  = { 64,128,128,128,128,192,128,128,128,192, 64};
  const int nc_[11]  = {128,128,128,128,128,128,128,128,129, 64,  3};
  const int k1_[11]  = { 63,128,128,128,128, 63,128,128,128, 27, 64};
  const int o1_[11]  = {  0,  0,  0,  0,  0,128,  0,  0,  0,128,  0};
  const int k2_[11]  = {999,999,999,999,999, 64,999,999,999, 64,999};
  const int do_[11]  = {0,8192,24576,40960,57344,73728,98304,114688,131072,149504,161792};

  int c = blockIdx.x;
  const float* src =
    c==0?s0: c==1?s1: c==2?s2: c==3?s3: c==4?s4: c==5?s5:
    c==6?s6: c==7?s7: c==8?s8: c==9?s9: s10;
  int nw=nw_[c], kw=kw_[c], nc=nc_[c], k1=k1_[c], o1=o1_[c], k2=k2_[c];
  int KS = kw >> 5;
  int total = nw * kw;
  for (int idx = blockIdx.y * blockDim.x + threadIdx.x; idx < total;
       idx += gridDim.y * blockDim.x) {
    int e   = idx & 7;
    int l15 = (idx >> 3) & 15;
    int lg  = (idx >> 7) & 3;
    int r   = idx >> 9;
    int ks  = r % KS;
    int nt  = r / KS;
    int n = nt * 16 + l15;
    int k = ks * 32 + lg * 8 + e;
    float v = 0.f;
    if (n < nc) {
      if (k < k1)       v = src[(o1 + k) * nc + n];
      else if (k >= k2) v = src[(k - k2) * nc + n];
    }
    dst[do_[c] + idx] = f2bf(v);
  }
}

// ---------------- posenc: 32 cols of one row, linear addresses (base + imm) ----------------
template<int I0, int L>
__device__ __forceinline__ void posenc_store(unsigned char* actb, int row,
                                             float p0, float p1, float p2)
{
#pragma unroll
  for (int q = 0; q < 4; q++) {
    float hv[8];
#pragma unroll
    for (int e = 0; e < 8; e++) {
      const int i = I0 + q * 8 + e;
      float v;
      if (i == 0) v = p0;
      else if (i == 1) v = p1;
      else if (i == 2) v = p2;
      else {
        const int idx = i - 3, j = idx / 6, t = idx % 6;
        if (j < L) {
          const float sc = (float)(1 << j);
          const float a  = (t % 3 == 0 ? p0 : (t % 3 == 1 ? p1 : p2)) * sc;
          v = (t < 3) ? __sinf(a) : __cosf(a);
        } else v = 0.f;
      }
      hv[e] = v;
    }
    uint4 pk;
    pk.x = pk2bf(hv[0], hv[1]);
    pk.y = pk2bf(hv[2], hv[3]);
    pk.z = pk2bf(hv[4], hv[5]);
    pk.w = pk2bf(hv[6], hv[7]);
    *(uint4*)(actb + row * ROWB + (I0 + q * 8) * 2) = pk;
  }
}

// ---------------- 2x2 tile layer: wave (wm,wn) computes rows [wm*64,+64) x ntiles [wn*4,+4) ----------------
// All LDS accesses: thread-const base + compile-time immediate (zero per-access VALU).
// rbase[mq] = (wm*64+mq*16+l15)*ROWB + lg*16 ; read imm = KB*2 + ks*64
// wbase[mq] = (wm*64+mq*16+l15)*ROWB + wn*128 + lg*8 ; write imm = DST*2 + nt*32
template<int KS, int KB, int DST, bool RELU, bool MIDBAR, bool SIG>
__device__ __forceinline__ void layer22(
    unsigned char* actb, const unsigned short* __restrict__ wchunk,
    const unsigned* rbase, const unsigned* wbase,
    int lane, int wid, float* __restrict__ out, long grow0)
{
  const int l15 = lane & 15;
  const int lg  = lane >> 4;
  const int wn  = wid & 1;
  const unsigned short* wl = wchunk + (wn * 4) * (KS * 512) + lane * 8;
  const f32x4 vzero = {0.f, 0.f, 0.f, 0.f};
  f32x4 acc[4][4];
#pragma unroll
  for (int a = 0; a < 4; a++)
#pragma unroll
    for (int b = 0; b < 4; b++) acc[a][b] = vzero;

#pragma unroll
  for (int ks = 0; ks < KS; ks++) {
    bf16x8 afr[4];
#pragma unroll
    for (int nt = 0; nt < 4; nt++)
      afr[nt] = *(const bf16x8*)(wl + (nt * KS + ks) * 512);
    bf16x8 bfr4[4];
#pragma unroll
    for (int mq = 0; mq < 4; mq++)
      bfr4[mq] = *(const bf16x8*)(actb + rbase[mq] + (KB * 2 + ks * 64));
#pragma unroll
    for (int nt = 0; nt < 4; nt++)
#pragma unroll
      for (int mq = 0; mq < 4; mq++)
        acc[mq][nt] = __builtin_amdgcn_mfma_f32_16x16x32_bf16(
            afr[nt], bfr4[mq], acc[mq][nt], 0, 0, 0);
  }

  f32x4 accs[2];
  if (SIG) {   // sigma tile (chunk nt==8), m-tiles {2*wid, 2*wid+1}; separate low-pressure loop
    accs[0] = vzero; accs[1] = vzero;
    unsigned sbase0 = ((2 * wid + 0) * 16 + l15) * ROWB + lg * 16;
    unsigned sbase1 = ((2 * wid + 1) * 16 + l15) * ROWB + lg * 16;
#pragma unroll
    for (int ks = 0; ks < KS; ks++) {
      bf16x8 afs = *(const bf16x8*)(wchunk + (8 * KS + ks) * 512 + lane * 8);
      bf16x8 b0 = *(const bf16x8*)(actb + sbase0 + (KB * 2 + ks * 64));
      bf16x8 b1 = *(const bf16x8*)(actb + sbase1 + (KB * 2 + ks * 64));
      accs[0] = __builtin_amdgcn_mfma_f32_16x16x32_bf16(afs, b0, accs[0], 0, 0, 0);
      accs[1] = __builtin_amdgcn_mfma_f32_16x16x32_bf16(afs, b1, accs[1], 0, 0, 0);
    }
  }

  if (MIDBAR) __syncthreads();     // all reads of old act done before any write

#pragma unroll
  for (int mq = 0; mq < 4; mq++) {
#pragma unroll
    for (int nt = 0; nt < 4; nt++) {
      f32x4 v = acc[mq][nt];
      if (RELU) {
        v.x = fmaxf(v.x, 0.f); v.y = fmaxf(v.y, 0.f);
        v.z = fmaxf(v.z, 0.f); v.w = fmaxf(v.w, 0.f);
      }
      uint2 pk;
      pk.x = pk2bf(v.x, v.y);
      pk.y = pk2bf(v.z, v.w);
      *(uint2*)(actb + wbase[mq] + (DST * 2 + nt * 32)) = pk;
    }
  }
  if (SIG && lg == 0) {
#pragma unroll
    for (int j = 0; j < 2; j++) {
      int m = (2 * wid + j) * 16 + l15;
      out[3L * NTOT + grow0 + m] = fmaxf(accs[j].x, 0.f);
    }
  }
  __syncthreads();                 // writes visible before next layer reads
}

// ---------------- b3_w0: full-row N-split (64 outputs, 1 ntile/wave), K=192 ----------------
__device__ __forceinline__ void layer_b3w0(
    unsigned char* actb, const unsigned short* __restrict__ wchunk,
    int lane, int wid)
{
  const int l15 = lane & 15;
  const int lg  = lane >> 4;
  const unsigned short* wl = wchunk + wid * (6 * 512) + lane * 8;
  const f32x4 vzero = {0.f, 0.f, 0.f, 0.f};
  f32x4 acc[8];
#pragma unroll
  for (int a = 0; a < 8; a++) acc[a] = vzero;

  unsigned rb[8];
#pragma unroll
  for (int mt = 0; mt < 8; mt++)
    rb[mt] = (mt * 16 + l15) * ROWB + lg * 16;

#pragma unroll
  for (int ks = 0; ks < 6; ks++) {
    bf16x8 afr = *(const bf16x8*)(wl + ks * 512);
#pragma unroll
    for (int half = 0; half < 2; half++) {
      bf16x8 bfr4[4];
#pragma unroll
      for (int mq = 0; mq < 4; mq++)
        bfr4[mq] = *(const bf16x8*)(actb + rb[half * 4 + mq] + ks * 64);
#pragma unroll
      for (int mq = 0; mq < 4; mq++)
        acc[half * 4 + mq] = __builtin_amdgcn_mfma_f32_16x16x32_bf16(
            afr, bfr4[mq], acc[half * 4 + mq], 0, 0, 0);
    }
  }

  __syncthreads();                 // reads done before writes

#pragma unroll
  for (int mt = 0; mt < 8; mt++) {
    f32x4 v = acc[mt];
    v.x = fmaxf(v.x, 0.f); v.y = fmaxf(v.y, 0.f);
    v.z = fmaxf(v.z, 0.f); v.w = fmaxf(v.w, 0.f);
    uint2 pk;
    pk.x = pk2bf(v.x, v.y);
    pk.y = pk2bf(v.z, v.w);
    *(uint2*)(actb + (mt * 16 + l15) * ROWB + wid * 32 + lg * 8) = pk;
  }
  __syncthreads();
}

// color: single n-tile, m-split {2*wid, 2*wid+1}; reads c1 cols 0..63; writes global only
__device__ __forceinline__ void color_n(
    unsigned char* actb, const unsigned short* __restrict__ wchunk,
    int lane, int wid, float* __restrict__ out, long grow0)
{
  const int l15 = lane & 15;
  const int lg  = lane >> 4;
  const f32x4 vzero = {0.f, 0.f, 0.f, 0.f};
  f32x4 acc[2];
  acc[0] = vzero; acc[1] = vzero;
  unsigned cb0 = ((2 * wid + 0) * 16 + l15) * ROWB + lg * 16;
  unsigned cb1 = ((2 * wid + 1) * 16 + l15) * ROWB + lg * 16;
#pragma unroll
  for (int ks = 0; ks < 2; ks++) {
    bf16x8 afr = *(const bf16x8*)(wchunk + ks * 512 + lane * 8);
    bf16x8 b0 = *(const bf16x8*)(actb + cb0 + ks * 64);
    bf16x8 b1 = *(const bf16x8*)(actb + cb1 + ks * 64);
    acc[0] = __builtin_amdgcn_mfma_f32_16x16x32_bf16(afr, b0, acc[0], 0, 0, 0);
    acc[1] = __builtin_amdgcn_mfma_f32_16x16x32_bf16(afr, b1, acc[1], 0, 0, 0);
  }
  if (lg == 0) {
#pragma unroll
    for (int j = 0; j < 2; j++) {
      int m = (2 * wid + j) * 16 + l15;
      long g3 = (grow0 + m) * 3;
      out[g3 + 0] = 1.f / (1.f + __expf(-acc[j].x));
      out[g3 + 1] = 1.f / (1.f + __expf(-acc[j].y));
      out[g3 + 2] = 1.f / (1.f + __expf(-acc[j].z));
    }
  }
}

__global__ __launch_bounds__(BLK, 2) void nerf_fused(
    const float* __restrict__ pos, const float* __restrict__ dirs,
    const unsigned short* __restrict__ wp, float* __restrict__ out)
{
  __shared__ unsigned char actb[ACT_BYTES];   // act[128][200 bf16-slots], linear rows

  const int tid   = threadIdx.x;
  const int lane  = tid & 63;
  const int wid   = tid >> 6;
  const int wm    = wid >> 1;                 // row half
  const int wn    = wid & 1;                  // col half
  const long grow0 = (long)blockIdx.x * MWG;

  const int l15 = lane & 15;
  const int lg  = lane >> 4;

  // per-thread LDS bases (computed once; all in-loop LDS addrs fold to base+imm)
  unsigned rbase[4], wbase[4];
#pragma unroll
  for (int mq = 0; mq < 4; mq++) {
    int m = wm * 64 + mq * 16 + l15;
    rbase[mq] = m * ROWB + lg * 16;
    wbase[mq] = m * ROWB + wn * 128 + lg * 8;
  }

  const int row = wid * 32 + (lane & 31);
  const long g  = grow0 + row;

  // posenc(pos) -> cols 0..62 (col 63 = 0), own rows
  {
    float p0 = pos[g * 3 + 0], p1 = pos[g * 3 + 1], p2 = pos[g * 3 + 2];
    if (lane < 32) posenc_store<0, 10>(actb, row, p0, p1, p2);
    else           posenc_store<32, 10>(actb, row, p0, p1, p2);
  }
  __syncthreads();

  // b1_w0: reads cols 0..63, writes 64..191 (disjoint -> no midbar)
  layer22<2, 0, 64, true, false, false>(actb, wp +      0, rbase, wbase, lane, wid, out, grow0);
  layer22<4, 64, 64, true, true, false>(actb, wp +   8192, rbase, wbase, lane, wid, out, grow0); // b1_w1
  layer22<4, 64, 64, true, true, false>(actb, wp +  24576, rbase, wbase, lane, wid, out, grow0); // b1_w2
  layer22<4, 64, 64, true, true, false>(actb, wp +  40960, rbase, wbase, lane, wid, out, grow0); // b1_w3
  layer22<4, 64, 64, true, true, false>(actb, wp +  57344, rbase, wbase, lane, wid, out, grow0); // b1_w4
  // b2_w0: K=192 reads 0..191, writes 64..191
  layer22<6, 0, 64, true, true, false>(actb, wp +  73728, rbase, wbase, lane, wid, out, grow0);

  // posenc(dirs) -> cols 0..26 (27..63 zero), own rows; consumed only by b3_w0 (after barriers)
  {
    float p0 = dirs[g * 3 + 0], p1 = dirs[g * 3 + 1], p2 = dirs[g * 3 + 2];
    if (lane < 32) posenc_store<0, 4>(actb, row, p0, p1, p2);
    else           posenc_store<32, 4>(actb, row, p0, p1, p2);   // all zeros
  }

  layer22<4, 64, 64, true, true, false>(actb, wp +  98304, rbase, wbase, lane, wid, out, grow0); // b2_w1
  layer22<4, 64, 64, true, true, false>(actb, wp + 114688, rbase, wbase, lane, wid, out, grow0); // b2_w2
  // b2_w3: feat (no relu) + sigma tile (SIG)
  layer22<4, 64, 64, false, true, true>(actb, wp + 131072, rbase, wbase, lane, wid, out, grow0);
  // b3_w0: K=192 reads 0..191 (d_emb|feat), writes c1 cols 0..63
  layer_b3w0(actb, wp + 149504, lane, wid);
  // b3_w1 -> color (global only)
  color_n(actb, wp + 161792, lane, wid, out, grow0);
}

extern "C" void kernel_launch(void* const* d_in, const int* in_sizes, int n_in,
                              void* d_out, int out_size, void* d_ws, size_t ws_size,
                              hipStream_t stream)
{
  const float* pos  = (const float*)d_in[0];
  const float* dirs = (const float*)d_in[1];
  unsigned short* wpack = (unsigned short*)d_ws;   // 325,632 B used
  float* out = (float*)d_out;

  prepack_k<<<dim3(11, 12, 1), 256, 0, stream>>>(
      (const float*)d_in[2], (const float*)d_in[3], (const float*)d_in[4],
      (const float*)d_in[5], (const float*)d_in[6], (const float*)d_in[7],
      (const float*)d_in[8], (const float*)d_in[9], (const float*)d_in[10],
      (const float*)d_in[11], (const float*)d_in[12], wpack);

  nerf_fused<<<NTOT / MWG, BLK, 0, stream>>>(pos, dirs, wpack, out);
}

// Round 18
// 331.249 us; speedup vs baseline: 2.6032x; 1.0036x over previous
//
#include <hip/hip_runtime.h>
#include <hip/hip_bf16.h>

#define NTOT  1048576
#define MWG   128          // rows per workgroup
#define BLK   256          // 4 waves in 2x2: wave (wm,wn) owns rows [wm*64,+64) x ntiles [wn*4,+4)
#define ROWB  400          // act row stride bytes; all LDS addrs = thread-const base + imm
#define ACT_BYTES  (MWG * ROWB)          // 51200; x3 blocks = 150 KB <= 160 KB

typedef __attribute__((ext_vector_type(8))) short  bf16x8;
typedef __attribute__((ext_vector_type(4))) float  f32x4;

__device__ __forceinline__ unsigned short f2bf(float f) {
  unsigned u = __float_as_uint(f);
  u += 0x7fffu + ((u >> 16) & 1u);          // RNE
  return (unsigned short)(u >> 16);
}

__device__ __forceinline__ unsigned pk2bf(float lo, float hi) {
  float2 t; t.x = lo; t.y = hi;
  __hip_bfloat162 b = __float22bfloat162_rn(t);   // RNE
  return *(unsigned*)&b;
}

// ---------------- weight prepack (identical to R6..R17) ----------------
__global__ __launch_bounds__(256) void prepack_k(
    const float* __restrict__ s0, const float* __restrict__ s1,
    const float* __restrict__ s2, const float* __restrict__ s3,
    const float* __restrict__ s4, const float* __restrict__ s5,
    const float* __restrict__ s6, const float* __restrict__ s7,
    const float* __restrict__ s8, const float* __restrict__ s9,
    const float* __restrict__ s10, unsigned short* __restrict__ dst)
{
  const int nw_[11]  = {128,128,128,128,128,128,128,128,144, 64, 16};
  const int kw_[11]  = { 64,128,128,128,128,192,128,128,128,192, 64};
  const int nc_[11]  = {128,128,128,128,128,128,128,128,129, 64,  3};
  const int k1_[11]  = { 63,128,128,128,128, 63,128,128,128, 27, 64};
  const int o1_[11]  = {  0,  0,  0,  0,  0,128,  0,  0,  0,128,  0};
  const int k2_[11]  = {999,999,999,999,999, 64,999,999,999, 64,999};
  const int do_[11]  = {0,8192,24576,40960,57344,73728,98304,114688,131072,149504,161792};

  int c = blockIdx.x;
  const float* src =
    c==0?s0: c==1?s1: c==2?s2: c==3?s3: c==4?s4: c==5?s5:
    c==6?s6: c==7?s7: c==8?s8: c==9?s9: s10;
  int nw=nw_[c], kw=kw_[c], nc=nc_[c], k1=k1_[c], o1=o1_[c], k2=k2_[c];
  int KS = kw >> 5;
  int total = nw * kw;
  for (int idx = blockIdx.y * blockDim.x + threadIdx.x; idx < total;
       idx += gridDim.y * blockDim.x) {
    int e   = idx & 7;
    int l15 = (idx >> 3) & 15;
    int lg  = (idx >> 7) & 3;
    int r   = idx >> 9;
    int ks  = r % KS;
    int nt  = r / KS;
    int n = nt * 16 + l15;
    int k = ks * 32 + lg * 8 + e;
    float v = 0.f;
    if (n < nc) {
      if (k < k1)       v = src[(o1 + k) * nc + n];
      else if (k >= k2) v = src[(k - k2) * nc + n];
    }
    dst[do_[c] + idx] = f2bf(v);
  }
}

// ---------------- posenc: 32 cols of one row, linear addresses (base + imm) ----------------
template<int I0, int L>
__device__ __forceinline__ void posenc_store(unsigned char* actb, int row,
                                             float p0, float p1, float p2)
{
#pragma unroll
  for (int q = 0; q < 4; q++) {
    float hv[8];
#pragma unroll
    for (int e = 0; e < 8; e++) {
      const int i = I0 + q * 8 + e;
      float v;
      if (i == 0) v = p0;
      else if (i == 1) v = p1;
      else if (i == 2) v = p2;
      else {
        const int idx = i - 3, j = idx / 6, t = idx % 6;
        if (j < L) {
          const float sc = (float)(1 << j);
          const float a  = (t % 3 == 0 ? p0 : (t % 3 == 1 ? p1 : p2)) * sc;
          v = (t < 3) ? __sinf(a) : __cosf(a);
        } else v = 0.f;
      }
      hv[e] = v;
    }
    uint4 pk;
    pk.x = pk2bf(hv[0], hv[1]);
    pk.y = pk2bf(hv[2], hv[3]);
    pk.z = pk2bf(hv[4], hv[5]);
    pk.w = pk2bf(hv[6], hv[7]);
    *(uint4*)(actb + row * ROWB + (I0 + q * 8) * 2) = pk;
  }
}

// ---------------- 2x2 tile layer ----------------
// All LDS accesses: thread-const base + compile-time immediate.
// ks=0 peeled: acc = mfma(a, b, vzero) -> no v_accvgpr_write zero-init block.
template<int KS, int KB, int DST, bool RELU, bool MIDBAR, bool SIG>
__device__ __forceinline__ void layer22(
    unsigned char* actb, const unsigned short* __restrict__ wchunk,
    const unsigned* rbase, const unsigned* wbase,
    int lane, int wid, float* __restrict__ out, long grow0)
{
  const int l15 = lane & 15;
  const int lg  = lane >> 4;
  const int wn  = wid & 1;
  const unsigned short* wl = wchunk + (wn * 4) * (KS * 512) + lane * 8;
  const f32x4 vzero = {0.f, 0.f, 0.f, 0.f};
  f32x4 acc[4][4];

  {                                    // ks = 0 peeled
    bf16x8 afr[4];
#pragma unroll
    for (int nt = 0; nt < 4; nt++)
      afr[nt] = *(const bf16x8*)(wl + (nt * KS) * 512);
    bf16x8 bfr4[4];
#pragma unroll
    for (int mq = 0; mq < 4; mq++)
      bfr4[mq] = *(const bf16x8*)(actb + rbase[mq] + KB * 2);
#pragma unroll
    for (int nt = 0; nt < 4; nt++)
#pragma unroll
      for (int mq = 0; mq < 4; mq++)
        acc[mq][nt] = __builtin_amdgcn_mfma_f32_16x16x32_bf16(
            afr[nt], bfr4[mq], vzero, 0, 0, 0);
  }
#pragma unroll
  for (int ks = 1; ks < KS; ks++) {
    bf16x8 afr[4];
#pragma unroll
    for (int nt = 0; nt < 4; nt++)
      afr[nt] = *(const bf16x8*)(wl + (nt * KS + ks) * 512);
    bf16x8 bfr4[4];
#pragma unroll
    for (int mq = 0; mq < 4; mq++)
      bfr4[mq] = *(const bf16x8*)(actb + rbase[mq] + (KB * 2 + ks * 64));
#pragma unroll
    for (int nt = 0; nt < 4; nt++)
#pragma unroll
      for (int mq = 0; mq < 4; mq++)
        acc[mq][nt] = __builtin_amdgcn_mfma_f32_16x16x32_bf16(
            afr[nt], bfr4[mq], acc[mq][nt], 0, 0, 0);
  }

  f32x4 accs[2];
  if (SIG) {   // sigma tile (chunk nt==8), m-tiles {2*wid, 2*wid+1}; ks=0 peeled
    unsigned sbase0 = ((2 * wid + 0) * 16 + l15) * ROWB + lg * 16;
    unsigned sbase1 = ((2 * wid + 1) * 16 + l15) * ROWB + lg * 16;
    {
      bf16x8 afs = *(const bf16x8*)(wchunk + (8 * KS) * 512 + lane * 8);
      bf16x8 b0 = *(const bf16x8*)(actb + sbase0 + KB * 2);
      bf16x8 b1 = *(const bf16x8*)(actb + sbase1 + KB * 2);
      accs[0] = __builtin_amdgcn_mfma_f32_16x16x32_bf16(afs, b0, vzero, 0, 0, 0);
      accs[1] = __builtin_amdgcn_mfma_f32_16x16x32_bf16(afs, b1, vzero, 0, 0, 0);
    }
#pragma unroll
    for (int ks = 1; ks < KS; ks++) {
      bf16x8 afs = *(const bf16x8*)(wchunk + (8 * KS + ks) * 512 + lane * 8);
      bf16x8 b0 = *(const bf16x8*)(actb + sbase0 + (KB * 2 + ks * 64));
      bf16x8 b1 = *(const bf16x8*)(actb + sbase1 + (KB * 2 + ks * 64));
      accs[0] = __builtin_amdgcn_mfma_f32_16x16x32_bf16(afs, b0, accs[0], 0, 0, 0);
      accs[1] = __builtin_amdgcn_mfma_f32_16x16x32_bf16(afs, b1, accs[1], 0, 0, 0);
    }
  }

  if (MIDBAR) __syncthreads();     // all reads of old act done before any write

#pragma unroll
  for (int mq = 0; mq < 4; mq++) {
#pragma unroll
    for (int nt = 0; nt < 4; nt++) {
      f32x4 v = acc[mq][nt];
      if (RELU) {
        v.x = fmaxf(v.x, 0.f); v.y = fmaxf(v.y, 0.f);
        v.z = fmaxf(v.z, 0.f); v.w = fmaxf(v.w, 0.f);
      }
      uint2 pk;
      pk.x = pk2bf(v.x, v.y);
      pk.y = pk2bf(v.z, v.w);
      *(uint2*)(actb + wbase[mq] + (DST * 2 + nt * 32)) = pk;
    }
  }
  if (SIG && lg == 0) {
#pragma unroll
    for (int j = 0; j < 2; j++) {
      int m = (2 * wid + j) * 16 + l15;
      out[3L * NTOT + grow0 + m] = fmaxf(accs[j].x, 0.f);
    }
  }
  __syncthreads();                 // writes visible before next layer reads
}

// ---------------- b3_w0: full-row N-split (64 outputs, 1 ntile/wave), K=192, ks=0 peeled ----------------
__device__ __forceinline__ void layer_b3w0(
    unsigned char* actb, const unsigned short* __restrict__ wchunk,
    int lane, int wid)
{
  const int l15 = lane & 15;
  const int lg  = lane >> 4;
  const unsigned short* wl = wchunk + wid * (6 * 512) + lane * 8;
  const f32x4 vzero = {0.f, 0.f, 0.f, 0.f};
  f32x4 acc[8];

  unsigned rb[8];
#pragma unroll
  for (int mt = 0; mt < 8; mt++)
    rb[mt] = (mt * 16 + l15) * ROWB + lg * 16;

  {                                    // ks = 0 peeled
    bf16x8 afr = *(const bf16x8*)(wl);
#pragma unroll
    for (int mt = 0; mt < 8; mt++) {
      bf16x8 b = *(const bf16x8*)(actb + rb[mt]);
      acc[mt] = __builtin_amdgcn_mfma_f32_16x16x32_bf16(afr, b, vzero, 0, 0, 0);
    }
  }
#pragma unroll
  for (int ks = 1; ks < 6; ks++) {
    bf16x8 afr = *(const bf16x8*)(wl + ks * 512);
#pragma unroll
    for (int half = 0; half < 2; half++) {
      bf16x8 bfr4[4];
#pragma unroll
      for (int mq = 0; mq < 4; mq++)
        bfr4[mq] = *(const bf16x8*)(actb + rb[half * 4 + mq] + ks * 64);
#pragma unroll
      for (int mq = 0; mq < 4; mq++)
        acc[half * 4 + mq] = __builtin_amdgcn_mfma_f32_16x16x32_bf16(
            afr, bfr4[mq], acc[half * 4 + mq], 0, 0, 0);
    }
  }

  __syncthreads();                 // reads done before writes

#pragma unroll
  for (int mt = 0; mt < 8; mt++) {
    f32x4 v = acc[mt];
    v.x = fmaxf(v.x, 0.f); v.y = fmaxf(v.y, 0.f);
    v.z = fmaxf(v.z, 0.f); v.w = fmaxf(v.w, 0.f);
    uint2 pk;
    pk.x = pk2bf(v.x, v.y);
    pk.y = pk2bf(v.z, v.w);
    *(uint2*)(actb + (mt * 16 + l15) * ROWB + wid * 32 + lg * 8) = pk;
  }
  __syncthreads();
}

// color: single n-tile, m-split {2*wid, 2*wid+1}; ks=0 peeled; writes global only
__device__ __forceinline__ void color_n(
    unsigned char* actb, const unsigned short* __restrict__ wchunk,
    int lane, int wid, float* __restrict__ out, long grow0)
{
  const int l15 = lane & 15;
  const int lg  = lane >> 4;
  const f32x4 vzero = {0.f, 0.f, 0.f, 0.f};
  f32x4 acc[2];
  unsigned cb0 = ((2 * wid + 0) * 16 + l15) * ROWB + lg * 16;
  unsigned cb1 = ((2 * wid + 1) * 16 + l15) * ROWB + lg * 16;
  {
    bf16x8 afr = *(const bf16x8*)(wchunk + lane * 8);
    bf16x8 b0 = *(const bf16x8*)(actb + cb0);
    bf16x8 b1 = *(const bf16x8*)(actb + cb1);
    acc[0] = __builtin_amdgcn_mfma_f32_16x16x32_bf16(afr, b0, vzero, 0, 0, 0);
    acc[1] = __builtin_amdgcn_mfma_f32_16x16x32_bf16(afr, b1, vzero, 0, 0, 0);
  }
  {
    bf16x8 afr = *(const bf16x8*)(wchunk + 512 + lane * 8);
    bf16x8 b0 = *(const bf16x8*)(actb + cb0 + 64);
    bf16x8 b1 = *(const bf16x8*)(actb + cb1 + 64);
    acc[0] = __builtin_amdgcn_mfma_f32_16x16x32_bf16(afr, b0, acc[0], 0, 0, 0);
    acc[1] = __builtin_amdgcn_mfma_f32_16x16x32_bf16(afr, b1, acc[1], 0, 0, 0);
  }
  if (lg == 0) {
#pragma unroll
    for (int j = 0; j < 2; j++) {
      int m = (2 * wid + j) * 16 + l15;
      long g3 = (grow0 + m) * 3;
      out[g3 + 0] = 1.f / (1.f + __expf(-acc[j].x));
      out[g3 + 1] = 1.f / (1.f + __expf(-acc[j].y));
      out[g3 + 2] = 1.f / (1.f + __expf(-acc[j].z));
    }
  }
}

__global__ __launch_bounds__(BLK, 2) void nerf_fused(
    const float* __restrict__ pos, const float* __restrict__ dirs,
    const unsigned short* __restrict__ wp, float* __restrict__ out)
{
  __shared__ unsigned char actb[ACT_BYTES];   // act[128][200 bf16-slots], linear rows

  const int tid   = threadIdx.x;
  const int lane  = tid & 63;
  const int wid   = tid >> 6;
  const int wm    = wid >> 1;                 // row half
  const int wn    = wid & 1;                  // col half
  const long grow0 = (long)blockIdx.x * MWG;

  const int l15 = lane & 15;
  const int lg  = lane >> 4;

  // per-thread LDS bases (computed once; all in-loop LDS addrs fold to base+imm)
  unsigned rbase[4], wbase[4];
#pragma unroll
  for (int mq = 0; mq < 4; mq++) {
    int m = wm * 64 + mq * 16 + l15;
    rbase[mq] = m * ROWB + lg * 16;
    wbase[mq] = m * ROWB + wn * 128 + lg * 8;
  }

  const int row = wid * 32 + (lane & 31);
  const long g  = grow0 + row;

  // posenc(pos) -> cols 0..62 (col 63 = 0), own rows
  {
    float p0 = pos[g * 3 + 0], p1 = pos[g * 3 + 1], p2 = pos[g * 3 + 2];
    if (lane < 32) posenc_store<0, 10>(actb, row, p0, p1, p2);
    else           posenc_store<32, 10>(actb, row, p0, p1, p2);
  }
  __syncthreads();

  // b1_w0: reads cols 0..63, writes 64..191 (disjoint -> no midbar)
  layer22<2, 0, 64, true, false, false>(actb, wp +      0, rbase, wbase, lane, wid, out, grow0);
  layer22<4, 64, 64, true, true, false>(actb, wp +   8192, rbase, wbase, lane, wid, out, grow0); // b1_w1
  layer22<4, 64, 64, true, true, false>(actb, wp +  24576, rbase, wbase, lane, wid, out, grow0); // b1_w2
  layer22<4, 64, 64, true, true, false>(actb, wp +  40960, rbase, wbase, lane, wid, out, grow0); // b1_w3
  layer22<4, 64, 64, true, true, false>(actb, wp +  57344, rbase, wbase, lane, wid, out, grow0); // b1_w4
  // b2_w0: K=192 reads 0..191, writes 64..191
  layer22<6, 0, 64, true, true, false>(actb, wp +  73728, rbase, wbase, lane, wid, out, grow0);

  // posenc(dirs) -> cols 0..26 (27..63 zero), own rows; consumed only by b3_w0 (after barriers)
  {
    float p0 = dirs[g * 3 + 0], p1 = dirs[g * 3 + 1], p2 = dirs[g * 3 + 2];
    if (lane < 32) posenc_store<0, 4>(actb, row, p0, p1, p2);
    else           posenc_store<32, 4>(actb, row, p0, p1, p2);   // all zeros
  }

  layer22<4, 64, 64, true, true, false>(actb, wp +  98304, rbase, wbase, lane, wid, out, grow0); // b2_w1
  layer22<4, 64, 64, true, true, false>(actb, wp + 114688, rbase, wbase, lane, wid, out, grow0); // b2_w2
  // b2_w3: feat (no relu) + sigma tile (SIG)
  layer22<4, 64, 64, false, true, true>(actb, wp + 131072, rbase, wbase, lane, wid, out, grow0);
  // b3_w0: K=192 reads 0..191 (d_emb|feat), writes c1 cols 0..63
  layer_b3w0(actb, wp + 149504, lane, wid);
  // b3_w1 -> color (global only)
  color_n(actb, wp + 161792, lane, wid, out, grow0);
}

extern "C" void kernel_launch(void* const* d_in, const int* in_sizes, int n_in,
                              void* d_out, int out_size, void* d_ws, size_t ws_size,
                              hipStream_t stream)
{
  const float* pos  = (const float*)d_in[0];
  const float* dirs = (const float*)d_in[1];
  unsigned short* wpack = (unsigned short*)d_ws;   // 325,632 B used
  float* out = (float*)d_out;

  prepack_k<<<dim3(11, 12, 1), 256, 0, stream>>>(
      (const float*)d_in[2], (const float*)d_in[3], (const float*)d_in[4],
      (const float*)d_in[5], (const float*)d_in[6], (const float*)d_in[7],
      (const float*)d_in[8], (const float*)d_in[9], (const float*)d_in[10],
      (const float*)d_in[11], (const float*)d_in[12], wpack);

  nerf_fused<<<NTOT / MWG, BLK, 0, stream>>>(pos, dirs, wpack, out);
}